// Round 1
// baseline (2887.834 us; speedup 1.0000x reference)
//
#include <hip/hip_runtime.h>
#include <math.h>

// ---- problem constants (fixed by the reference) ----
constexpr int N_NODES = 20000;
constexpr int N_EDGES = 320000;
constexpr int N_GRAPH = 200;
constexpr int F_IN    = 128;
constexpr int NH      = 4;
constexpr int O1 = 64,  O2 = 128, O3 = 256;
constexpr int D1 = 256, D2 = 512, D3 = 1024;
constexpr int LAT  = 128;
constexpr int HIDG = 128;      // gate MLP hidden
constexpr float NEG_SLOPE = 0.2f;

// ---------------- utility kernels ----------------
__global__ void fill_kernel(float* __restrict__ p, float v, int n) {
    int i = blockIdx.x * blockDim.x + threadIdx.x;
    if (i < n) p[i] = v;
}

__device__ inline void atomicMaxFloat(float* addr, float val) {
    int* ia = (int*)addr;
    int old = *ia;
    while (__int_as_float(old) < val) {
        int assumed = old;
        old = atomicCAS(ia, assumed, __float_as_int(val));
        if (old == assumed) break;
    }
}

// ---------------- fp32 tiled GEMM: C[M,Nn] = A[M,K] @ B[K,Nn] ----------------
// BM=BN=64, BK=16, 256 threads, 4x4 per thread. K % 16 == 0, Nn % 64 == 0.
template<bool RELU, bool BIAS>
__global__ __launch_bounds__(256)
void gemm64(const float* __restrict__ A, const float* __restrict__ B,
            const float* __restrict__ bias, float* __restrict__ C,
            int M, int Nn, int K) {
    constexpr int BM = 64, BN = 64, BK = 16;
    __shared__ float As[BK][BM];   // transposed: As[k][row]
    __shared__ float Bs[BK][BN];

    const int tid = threadIdx.x;
    const int tx = tid % 16, ty = tid / 16;
    const int brow = blockIdx.y * BM, bcol = blockIdx.x * BN;

    float acc[4][4] = {};

    const int arow  = tid / 4;          // 0..63
    const int acol  = (tid % 4) * 4;    // 0,4,8,12
    const int browA = brow + arow;
    const int brB   = tid / 16;         // 0..15
    const int bcB   = (tid % 16) * 4;

    for (int k0 = 0; k0 < K; k0 += BK) {
        float4 av = make_float4(0.f, 0.f, 0.f, 0.f);
        if (browA < M)
            av = *(const float4*)&A[(size_t)browA * K + k0 + acol];
        As[acol + 0][arow] = av.x;
        As[acol + 1][arow] = av.y;
        As[acol + 2][arow] = av.z;
        As[acol + 3][arow] = av.w;
        float4 bv = *(const float4*)&B[(size_t)(k0 + brB) * Nn + bcol + bcB];
        *(float4*)&Bs[brB][bcB] = bv;
        __syncthreads();
        #pragma unroll
        for (int k = 0; k < BK; ++k) {
            float ra[4], rb[4];
            #pragma unroll
            for (int i = 0; i < 4; ++i) ra[i] = As[k][ty * 4 + i];
            #pragma unroll
            for (int j = 0; j < 4; ++j) rb[j] = Bs[k][tx * 4 + j];
            #pragma unroll
            for (int i = 0; i < 4; ++i)
                #pragma unroll
                for (int j = 0; j < 4; ++j)
                    acc[i][j] += ra[i] * rb[j];
        }
        __syncthreads();
    }

    #pragma unroll
    for (int i = 0; i < 4; ++i) {
        int r = brow + ty * 4 + i;
        if (r >= M) break;
        #pragma unroll
        for (int j = 0; j < 4; ++j) {
            int c = bcol + tx * 4 + j;
            float v = acc[i][j];
            if (BIAS) v += bias[c];
            if (RELU) v = fmaxf(v, 0.f);
            C[(size_t)r * Nn + c] = v;
        }
    }
}

// ---------------- per-node attention halves: el/er [N,H] ----------------
// block = 256 (4 waves), one block per node, wave h handles head h
__global__ __launch_bounds__(256)
void attn_lr(const float* __restrict__ feat, const float* __restrict__ al,
             const float* __restrict__ ar, float* __restrict__ el,
             float* __restrict__ er, int O) {
    int n = blockIdx.x;
    int h = threadIdx.x >> 6;
    int lane = threadIdx.x & 63;
    const float* fr = feat + (size_t)n * (NH * O) + h * O;
    float sl = 0.f, sr = 0.f;
    for (int o = lane; o < O; o += 64) {
        float f = fr[o];
        sl += f * al[h * O + o];
        sr += f * ar[h * O + o];
    }
    #pragma unroll
    for (int off = 32; off; off >>= 1) {
        sl += __shfl_down(sl, off);
        sr += __shfl_down(sr, off);
    }
    if (lane == 0) {
        el[n * NH + h] = sl;
        er[n * NH + h] = sr;
    }
}

// ---------------- edge pass A: e = leaky_relu(el[src]+er[dst]); segment max ----
__global__ void edge_a(const float* __restrict__ el, const float* __restrict__ er,
                       const int* __restrict__ src, const int* __restrict__ dst,
                       float* __restrict__ eatt, float* __restrict__ emax) {
    int t = blockIdx.x * blockDim.x + threadIdx.x;
    if (t >= N_EDGES * NH) return;
    int ei = t >> 2, h = t & 3;
    int s = src[ei], d = dst[ei];
    float v = el[s * NH + h] + er[d * NH + h];
    v = (v >= 0.f) ? v : NEG_SLOPE * v;
    eatt[t] = v;
    atomicMaxFloat(&emax[d * NH + h], v);
}

// ---------------- edge pass B: ex = exp(e - emax[dst]); segment sum ----------
__global__ void edge_b(float* __restrict__ eatt, const float* __restrict__ emax,
                       float* __restrict__ denom, const int* __restrict__ dst) {
    int t = blockIdx.x * blockDim.x + threadIdx.x;
    if (t >= N_EDGES * NH) return;
    int ei = t >> 2, h = t & 3;
    int d = dst[ei];
    float v = expf(eatt[t] - emax[d * NH + h]);
    eatt[t] = v;
    atomicAdd(&denom[d * NH + h], v);
}

// ---------------- edge pass C: rst[dst] += feat[src] * alpha ----------------
// one block (256 threads) per edge
__global__ __launch_bounds__(256)
void scatter_msg(const float* __restrict__ feat, const float* __restrict__ eatt,
                 const float* __restrict__ denom, const int* __restrict__ src,
                 const int* __restrict__ dst, float* __restrict__ rst,
                 int oshift, int D) {
    int e = blockIdx.x;
    int s = src[e], d = dst[e];
    __shared__ float alpha[NH];
    if (threadIdx.x < NH) {
        float dn = denom[d * NH + threadIdx.x];
        alpha[threadIdx.x] = eatt[e * NH + threadIdx.x] / fmaxf(dn, 1e-9f);
    }
    __syncthreads();
    const float* fs = feat + (size_t)s * D;
    float* rd = rst + (size_t)d * D;
    for (int t = threadIdx.x; t < D; t += 256) {
        int h = t >> oshift;
        atomicAdd(&rd[t], fs[t] * alpha[h]);
    }
}

// ---------------- node finish: h = elu(rst + b) (in-place ok) ----------------
__global__ void finish_elu(const float* __restrict__ rst, const float* __restrict__ b,
                           float* __restrict__ h, int total, int D) {
    int i = blockIdx.x * blockDim.x + threadIdx.x;
    if (i >= total) return;
    float v = rst[i] + b[i % D];
    h[i] = (v > 0.f) ? v : expm1f(v);
}

// ---------------- gate scalar: gate[n] = gh[n,:]·Wg2 + bg2; graph max -------
__global__ __launch_bounds__(128)
void gate_kernel(const float* __restrict__ gh, const float* __restrict__ Wg2,
                 const float* __restrict__ bg2, const int* __restrict__ gid,
                 float* __restrict__ gate, float* __restrict__ gmax) {
    int n = blockIdx.x;
    int t = threadIdx.x;                 // 128
    __shared__ float red[128];
    red[t] = gh[(size_t)n * HIDG + t] * Wg2[t];
    __syncthreads();
    for (int s = 64; s; s >>= 1) {
        if (t < s) red[t] += red[t + s];
        __syncthreads();
    }
    if (t == 0) {
        float g = red[0] + bg2[0];
        gate[n] = g;
        atomicMaxFloat(&gmax[gid[n]], g);
    }
}

__global__ void gexp_kernel(const float* __restrict__ gate, const float* __restrict__ gmax,
                            const int* __restrict__ gid, float* __restrict__ gexp,
                            float* __restrict__ gsum) {
    int n = blockIdx.x * blockDim.x + threadIdx.x;
    if (n >= N_NODES) return;
    float v = expf(gate[n] - gmax[gid[n]]);
    gexp[n] = v;
    atomicAdd(&gsum[gid[n]], v);
}

// ---------------- graph embedding scatter: gemb[g] += a[n] * h3[n] ----------
__global__ __launch_bounds__(256)
void scatter_emb(const float* __restrict__ gexp, const float* __restrict__ gsum,
                 const int* __restrict__ gid, const float* __restrict__ h3,
                 float* __restrict__ gemb) {
    int n = blockIdx.x;
    int g = gid[n];
    float a = gexp[n] / fmaxf(gsum[g], 1e-9f);
    const float* hr = h3 + (size_t)n * D3;
    float* gr = gemb + (size_t)g * D3;
    for (int d = threadIdx.x; d < D3; d += 256)
        atomicAdd(&gr[d], a * hr[d]);
}

// ---------------- heads: mu/lv = gemb @ Wmu/Wlv + b --------------------------
__global__ __launch_bounds__(128)
void heads_kernel(const float* __restrict__ gemb, const float* __restrict__ Wmu,
                  const float* __restrict__ bmu, const float* __restrict__ Wlv,
                  const float* __restrict__ blv, float* __restrict__ out) {
    int g = blockIdx.x;
    int j = threadIdx.x;                 // 128
    __shared__ float e[D3];
    for (int k = threadIdx.x; k < D3; k += 128) e[k] = gemb[(size_t)g * D3 + k];
    __syncthreads();
    float smu = 0.f, slv = 0.f;
    for (int k = 0; k < D3; ++k) {
        float v = e[k];
        smu += v * Wmu[k * LAT + j];
        slv += v * Wlv[k * LAT + j];
    }
    out[g * LAT + j] = smu + bmu[j];
    out[N_GRAPH * LAT + g * LAT + j] = slv + blv[j];
}

// ---------------- host launch ----------------
extern "C" void kernel_launch(void* const* d_in, const int* in_sizes, int n_in,
                              void* d_out, int out_size, void* d_ws, size_t ws_size,
                              hipStream_t stream) {
    const float* node_feat = (const float*)d_in[0];
    const int*   src = (const int*)d_in[1];
    const int*   dst = (const int*)d_in[2];
    const int*   gid = (const int*)d_in[3];
    const float* W1  = (const float*)d_in[4];
    const float* al1 = (const float*)d_in[5];
    const float* ar1 = (const float*)d_in[6];
    const float* b1  = (const float*)d_in[7];
    const float* W2  = (const float*)d_in[8];
    const float* al2 = (const float*)d_in[9];
    const float* ar2 = (const float*)d_in[10];
    const float* b2  = (const float*)d_in[11];
    const float* W3  = (const float*)d_in[12];
    const float* al3 = (const float*)d_in[13];
    const float* ar3 = (const float*)d_in[14];
    const float* b3  = (const float*)d_in[15];
    const float* Wg1 = (const float*)d_in[16];
    const float* bg1 = (const float*)d_in[17];
    const float* Wg2 = (const float*)d_in[18];
    const float* bg2 = (const float*)d_in[19];
    const float* Wmu = (const float*)d_in[20];
    const float* bmu = (const float*)d_in[21];
    const float* Wlv = (const float*)d_in[22];
    const float* blv = (const float*)d_in[23];
    float* out = (float*)d_out;

    float* ws = (float*)d_ws;
    float* bufA  = ws;                                    // N*D3 (feat buffer)
    float* bufB  = bufA + (size_t)N_NODES * D3;           // N*D3 (rst / h buffer)
    float* el    = bufB + (size_t)N_NODES * D3;
    float* er    = el + N_NODES * NH;
    float* emax  = er + N_NODES * NH;
    float* denom = emax + N_NODES * NH;
    float* eatt  = denom + N_NODES * NH;                  // E*NH
    float* gh    = eatt + (size_t)N_EDGES * NH;           // N*HIDG
    float* gate  = gh + (size_t)N_NODES * HIDG;
    float* gexp  = gate + N_NODES;
    float* gmaxb = gexp + N_NODES;
    float* gsum  = gmaxb + N_GRAPH;
    float* gemb  = gsum + N_GRAPH;                        // G*D3

    auto fill = [&](float* p, float v, int n) {
        fill_kernel<<<dim3((n + 255) / 256), dim3(256), 0, stream>>>(p, v, n);
    };

    auto gat = [&](const float* X, const float* W, const float* al, const float* ar,
                   const float* b, float* F, float* R, int K, int O, int D, int oshift) {
        dim3 gg(D / 64, (N_NODES + 63) / 64);
        gemm64<false, false><<<gg, dim3(256), 0, stream>>>(X, W, nullptr, F, N_NODES, D, K);
        attn_lr<<<dim3(N_NODES), dim3(256), 0, stream>>>(F, al, ar, el, er, O);
        fill(emax, -INFINITY, N_NODES * NH);
        fill(denom, 0.f, N_NODES * NH);
        fill(R, 0.f, N_NODES * D);   // R may alias X: X only read by the GEMM (already ordered before)
        int et = N_EDGES * NH;
        edge_a<<<dim3((et + 255) / 256), dim3(256), 0, stream>>>(el, er, src, dst, eatt, emax);
        edge_b<<<dim3((et + 255) / 256), dim3(256), 0, stream>>>(eatt, emax, denom, dst);
        scatter_msg<<<dim3(N_EDGES), dim3(256), 0, stream>>>(F, eatt, denom, src, dst, R, oshift, D);
        int tot = N_NODES * D;
        finish_elu<<<dim3((tot + 255) / 256), dim3(256), 0, stream>>>(R, b, R, tot, D);
    };

    // layer 1: X = node_feat, F = bufA, R = bufB  -> h1 in bufB
    gat(node_feat, W1, al1, ar1, b1, bufA, bufB, F_IN, O1, D1, 6);
    // layer 2: X = bufB(h1), F = bufA, R = bufB   -> h2 in bufB
    gat(bufB, W2, al2, ar2, b2, bufA, bufB, D1, O2, D2, 7);
    // layer 3: X = bufB(h2), F = bufA, R = bufB   -> h3 in bufB
    gat(bufB, W3, al3, ar3, b3, bufA, bufB, D2, O3, D3, 8);

    // pooling: gate hidden = relu(h3 @ Wg1 + bg1)
    {
        dim3 gg(HIDG / 64, (N_NODES + 63) / 64);
        gemm64<true, true><<<gg, dim3(256), 0, stream>>>(bufB, Wg1, bg1, gh, N_NODES, HIDG, D3);
    }
    fill(gmaxb, -INFINITY, N_GRAPH);
    fill(gsum, 0.f, N_GRAPH);
    fill(gemb, 0.f, N_GRAPH * D3);
    gate_kernel<<<dim3(N_NODES), dim3(128), 0, stream>>>(gh, Wg2, bg2, gid, gate, gmaxb);
    gexp_kernel<<<dim3((N_NODES + 255) / 256), dim3(256), 0, stream>>>(gate, gmaxb, gid, gexp, gsum);
    scatter_emb<<<dim3(N_NODES), dim3(256), 0, stream>>>(gexp, gsum, gid, bufB, gemb);
    heads_kernel<<<dim3(N_GRAPH), dim3(128), 0, stream>>>(gemb, Wmu, bmu, Wlv, blv, out);
}

// Round 2
// 1128.821 us; speedup vs baseline: 2.5583x; 2.5583x over previous
//
#include <hip/hip_runtime.h>
#include <math.h>

// ---- problem constants (fixed by the reference) ----
constexpr int N_NODES = 20000;
constexpr int N_EDGES = 320000;
constexpr int N_GRAPH = 200;
constexpr int F_IN    = 128;
constexpr int NH      = 4;
constexpr int O1 = 64,  O2 = 128, O3 = 256;
constexpr int D1 = 256, D2 = 512, D3 = 1024;
constexpr int LAT  = 128;
constexpr int HIDG = 128;      // gate MLP hidden
constexpr float NEG_SLOPE = 0.2f;

// ================= CSR build =================
__global__ void zero_int(int* __restrict__ p, int n) {
    int i = blockIdx.x * blockDim.x + threadIdx.x;
    if (i < n) p[i] = 0;
}

__global__ void count_deg(const int* __restrict__ dst, int* __restrict__ deg) {
    int e = blockIdx.x * blockDim.x + threadIdx.x;
    if (e < N_EDGES) atomicAdd(&deg[dst[e]], 1);
}

constexpr int SCAN_B = 512;
__global__ __launch_bounds__(SCAN_B)
void scan1(const int* __restrict__ deg, int* __restrict__ rowptr, int* __restrict__ bsum) {
    __shared__ int s[SCAN_B];
    int tid = threadIdx.x;
    int i = blockIdx.x * SCAN_B + tid;
    int v = (i < N_NODES) ? deg[i] : 0;
    s[tid] = v;
    __syncthreads();
    for (int off = 1; off < SCAN_B; off <<= 1) {
        int add = (tid >= off) ? s[tid - off] : 0;
        __syncthreads();
        s[tid] += add;
        __syncthreads();
    }
    if (i < N_NODES) rowptr[i] = s[tid] - v;   // exclusive
    if (tid == SCAN_B - 1) bsum[blockIdx.x] = s[tid];
}

__global__ void scan2(const int* __restrict__ bsum, int* __restrict__ boff, int nblk) {
    if (threadIdx.x == 0 && blockIdx.x == 0) {
        int run = 0;
        for (int b = 0; b < nblk; ++b) { boff[b] = run; run += bsum[b]; }
    }
}

__global__ __launch_bounds__(SCAN_B)
void scan3(int* __restrict__ rowptr, const int* __restrict__ boff, int* __restrict__ pos) {
    int i = blockIdx.x * SCAN_B + threadIdx.x;
    if (i < N_NODES) {
        int v = rowptr[i] + boff[blockIdx.x];
        rowptr[i] = v;
        pos[i] = v;
    }
    if (i == 0) rowptr[N_NODES] = N_EDGES;
}

__global__ void fill_csr(const int* __restrict__ src, const int* __restrict__ dst,
                         int* __restrict__ pos, int* __restrict__ csr_src) {
    int e = blockIdx.x * blockDim.x + threadIdx.x;
    if (e >= N_EDGES) return;
    int slot = atomicAdd(&pos[dst[e]], 1);
    csr_src[slot] = src[e];
}

// graph boundaries: gptr[g] = lower_bound(gid, g), gid is sorted
__global__ void gptr_kernel(const int* __restrict__ gid, int* __restrict__ gptr) {
    int g = blockIdx.x * blockDim.x + threadIdx.x;
    if (g > N_GRAPH) return;
    int lo = 0, hi = N_NODES;
    while (lo < hi) { int mid = (lo + hi) >> 1; if (gid[mid] < g) lo = mid + 1; else hi = mid; }
    gptr[g] = lo;
}

// ================= fp32 GEMM 128x128x8 =================
// C[M,Nn] = A[M,K] @ B[K,Nn] (+bias, relu). Nn%128==0, K%8==0.
template<bool RELU, bool BIAS>
__global__ __launch_bounds__(256)
void gemm128(const float* __restrict__ A, const float* __restrict__ B,
             const float* __restrict__ bias, float* __restrict__ C,
             int M, int Nn, int K) {
    constexpr int BM = 128, BN = 128, BK = 8;
    __shared__ float As[BK][BM + 4];   // pad 4 keeps 16B alignment, kills write conflicts
    __shared__ float Bs[BK][BN];

    const int tid = threadIdx.x;
    const int tx = tid % 16, ty = tid / 16;
    const int brow = blockIdx.y * BM, bcol = blockIdx.x * BN;

    // A staging: row = tid/2 (0..127), kgrp = (tid%2)*4
    const int arow = tid >> 1;
    const int akg  = (tid & 1) * 4;
    const int garow = brow + arow;
    // B staging: krow = tid/32 (0..7), col = (tid%32)*4
    const int bkr = tid >> 5;
    const int bcl = (tid & 31) * 4;

    float acc[8][8] = {};

    for (int k0 = 0; k0 < K; k0 += BK) {
        float4 av = make_float4(0.f, 0.f, 0.f, 0.f);
        if (garow < M)
            av = *(const float4*)&A[(size_t)garow * K + k0 + akg];
        As[akg + 0][arow] = av.x;
        As[akg + 1][arow] = av.y;
        As[akg + 2][arow] = av.z;
        As[akg + 3][arow] = av.w;
        float4 bv = *(const float4*)&B[(size_t)(k0 + bkr) * Nn + bcol + bcl];
        *(float4*)&Bs[bkr][bcl] = bv;
        __syncthreads();
        #pragma unroll
        for (int k = 0; k < BK; ++k) {
            float ra[8], rb[8];
            *(float4*)&ra[0] = *(const float4*)&As[k][ty * 8];
            *(float4*)&ra[4] = *(const float4*)&As[k][ty * 8 + 4];
            *(float4*)&rb[0] = *(const float4*)&Bs[k][tx * 8];
            *(float4*)&rb[4] = *(const float4*)&Bs[k][tx * 8 + 4];
            #pragma unroll
            for (int i = 0; i < 8; ++i)
                #pragma unroll
                for (int j = 0; j < 8; ++j)
                    acc[i][j] += ra[i] * rb[j];
        }
        __syncthreads();
    }

    #pragma unroll
    for (int i = 0; i < 8; ++i) {
        int r = brow + ty * 8 + i;
        if (r < M) {
            float* crow = &C[(size_t)r * Nn + bcol + tx * 8];
            #pragma unroll
            for (int j = 0; j < 8; ++j) {
                float v = acc[i][j];
                if (BIAS) v += bias[bcol + tx * 8 + j];
                if (RELU) v = fmaxf(v, 0.f);
                crow[j] = v;
            }
        }
    }
}

// ================= per-node attention halves =================
__global__ __launch_bounds__(256)
void attn_lr(const float* __restrict__ feat, const float* __restrict__ al,
             const float* __restrict__ ar, float* __restrict__ el,
             float* __restrict__ er, int O) {
    int n = blockIdx.x;
    int h = threadIdx.x >> 6;
    int lane = threadIdx.x & 63;
    const float* fr = feat + (size_t)n * (NH * O) + h * O;
    float sl = 0.f, sr = 0.f;
    for (int o = lane; o < O; o += 64) {
        float f = fr[o];
        sl += f * al[h * O + o];
        sr += f * ar[h * O + o];
    }
    #pragma unroll
    for (int off = 32; off; off >>= 1) {
        sl += __shfl_down(sl, off);
        sr += __shfl_down(sr, off);
    }
    if (lane == 0) {
        el[n * NH + h] = sl;
        er[n * NH + h] = sr;
    }
}

// ================= per-dst edge softmax over CSR =================
// one wave per dst node; csr_e[slot][h] ends up holding exp(e - max),
// rden[d][h] = 1/max(sum,1e-9)
__global__ __launch_bounds__(64)
void attn_softmax(const float* __restrict__ el, const float* __restrict__ er,
                  const int* __restrict__ rowptr, const int* __restrict__ csr_src,
                  float* __restrict__ csr_e, float* __restrict__ rden) {
    int d = blockIdx.x;
    int lane = threadIdx.x;
    int base = rowptr[d], end = rowptr[d + 1];
    float erd[NH];
    #pragma unroll
    for (int h = 0; h < NH; ++h) erd[h] = er[d * NH + h];

    float mx[NH] = {-INFINITY, -INFINITY, -INFINITY, -INFINITY};
    for (int s = base + lane; s < end; s += 64) {
        int sn = csr_src[s];
        #pragma unroll
        for (int h = 0; h < NH; ++h) {
            float v = el[sn * NH + h] + erd[h];
            v = (v >= 0.f) ? v : NEG_SLOPE * v;
            csr_e[s * NH + h] = v;
            mx[h] = fmaxf(mx[h], v);
        }
    }
    #pragma unroll
    for (int h = 0; h < NH; ++h)
        #pragma unroll
        for (int off = 32; off; off >>= 1)
            mx[h] = fmaxf(mx[h], __shfl_xor(mx[h], off));

    float sm[NH] = {0.f, 0.f, 0.f, 0.f};
    for (int s = base + lane; s < end; s += 64) {
        #pragma unroll
        for (int h = 0; h < NH; ++h) {
            float ex = expf(csr_e[s * NH + h] - mx[h]);
            csr_e[s * NH + h] = ex;
            sm[h] += ex;
        }
    }
    #pragma unroll
    for (int h = 0; h < NH; ++h)
        #pragma unroll
        for (int off = 32; off; off >>= 1)
            sm[h] += __shfl_xor(sm[h], off);

    if (lane == 0) {
        #pragma unroll
        for (int h = 0; h < NH; ++h)
            rden[d * NH + h] = 1.f / fmaxf(sm[h], 1e-9f);
    }
}

// ================= gather aggregation (per dst node) =================
// out[d] = elu( (sum_e ex_e * feat[src_e]) * rden[d] + bias )
template<int REGS, int OSHIFT>
__global__ __launch_bounds__(256)
void aggregate(const float* __restrict__ feat, const float* __restrict__ csr_e,
               const float* __restrict__ rden, const int* __restrict__ rowptr,
               const int* __restrict__ csr_src, const float* __restrict__ bias,
               float* __restrict__ out, int D) {
    int d = blockIdx.x;
    int t = threadIdx.x;
    int base = rowptr[d], end = rowptr[d + 1];
    const int col0 = t * REGS;
    const int h = col0 >> OSHIFT;    // all REGS cols of this thread share one head

    float acc[REGS];
    #pragma unroll
    for (int k = 0; k < REGS; ++k) acc[k] = 0.f;

    for (int s = base; s < end; ++s) {
        int sn = csr_src[s];
        float a = csr_e[s * NH + h];
        const float* fr = feat + (size_t)sn * D + col0;
        if (REGS == 4) {
            float4 f = *(const float4*)fr;
            acc[0] += f.x * a; acc[1] += f.y * a; acc[2] += f.z * a; acc[3] += f.w * a;
        } else if (REGS == 2) {
            float2 f = *(const float2*)fr;
            acc[0] += f.x * a; acc[1] += f.y * a;
        } else {
            acc[0] += fr[0] * a;
        }
    }

    float rd = rden[d * NH + h];
    float* orow = out + (size_t)d * D + col0;
    #pragma unroll
    for (int k = 0; k < REGS; ++k) {
        float v = acc[k] * rd + bias[col0 + k];
        orow[k] = (v > 0.f) ? v : expm1f(v);
    }
}

// ================= gate scalar =================
__global__ __launch_bounds__(128)
void gate_kernel(const float* __restrict__ gh, const float* __restrict__ Wg2,
                 const float* __restrict__ bg2, float* __restrict__ gate) {
    int n = blockIdx.x;
    int t = threadIdx.x;                 // 128
    __shared__ float red[128];
    red[t] = gh[(size_t)n * HIDG + t] * Wg2[t];
    __syncthreads();
    for (int s = 64; s; s >>= 1) {
        if (t < s) red[t] += red[t + s];
        __syncthreads();
    }
    if (t == 0) gate[n] = red[0] + bg2[0];
}

// per-graph softmax over nodes -> anorm[n]
__global__ __launch_bounds__(64)
void gate_stats(const float* __restrict__ gate, const int* __restrict__ gptr,
                float* __restrict__ anorm) {
    int g = blockIdx.x;
    int lane = threadIdx.x;
    int s = gptr[g], e = gptr[g + 1];
    float m = -INFINITY;
    for (int n = s + lane; n < e; n += 64) m = fmaxf(m, gate[n]);
    #pragma unroll
    for (int off = 32; off; off >>= 1) m = fmaxf(m, __shfl_xor(m, off));
    float sum = 0.f;
    for (int n = s + lane; n < e; n += 64) sum += expf(gate[n] - m);
    #pragma unroll
    for (int off = 32; off; off >>= 1) sum += __shfl_xor(sum, off);
    float inv = 1.f / fmaxf(sum, 1e-9f);
    for (int n = s + lane; n < e; n += 64) anorm[n] = expf(gate[n] - m) * inv;
}

// gemb[g] = sum_n anorm[n] * h3[n]
__global__ __launch_bounds__(256)
void pool_gather(const float* __restrict__ h3, const float* __restrict__ anorm,
                 const int* __restrict__ gptr, float* __restrict__ gemb) {
    int g = blockIdx.y;
    int col = blockIdx.x * 256 + threadIdx.x;
    float acc = 0.f;
    int s = gptr[g], e = gptr[g + 1];
    for (int n = s; n < e; ++n)
        acc += anorm[n] * h3[(size_t)n * D3 + col];
    gemb[(size_t)g * D3 + col] = acc;
}

// ================= heads =================
__global__ __launch_bounds__(128)
void heads_kernel(const float* __restrict__ gemb, const float* __restrict__ Wmu,
                  const float* __restrict__ bmu, const float* __restrict__ Wlv,
                  const float* __restrict__ blv, float* __restrict__ out) {
    int g = blockIdx.x;
    int j = threadIdx.x;                 // 128
    __shared__ float e[D3];
    for (int k = threadIdx.x; k < D3; k += 128) e[k] = gemb[(size_t)g * D3 + k];
    __syncthreads();
    float smu = 0.f, slv = 0.f;
    for (int k = 0; k < D3; ++k) {
        float v = e[k];
        smu += v * Wmu[k * LAT + j];
        slv += v * Wlv[k * LAT + j];
    }
    out[g * LAT + j] = smu + bmu[j];
    out[N_GRAPH * LAT + g * LAT + j] = slv + blv[j];
}

// ================= host launch =================
extern "C" void kernel_launch(void* const* d_in, const int* in_sizes, int n_in,
                              void* d_out, int out_size, void* d_ws, size_t ws_size,
                              hipStream_t stream) {
    const float* node_feat = (const float*)d_in[0];
    const int*   src = (const int*)d_in[1];
    const int*   dst = (const int*)d_in[2];
    const int*   gid = (const int*)d_in[3];
    const float* W1  = (const float*)d_in[4];
    const float* al1 = (const float*)d_in[5];
    const float* ar1 = (const float*)d_in[6];
    const float* b1  = (const float*)d_in[7];
    const float* W2  = (const float*)d_in[8];
    const float* al2 = (const float*)d_in[9];
    const float* ar2 = (const float*)d_in[10];
    const float* b2  = (const float*)d_in[11];
    const float* W3  = (const float*)d_in[12];
    const float* al3 = (const float*)d_in[13];
    const float* ar3 = (const float*)d_in[14];
    const float* b3  = (const float*)d_in[15];
    const float* Wg1 = (const float*)d_in[16];
    const float* bg1 = (const float*)d_in[17];
    const float* Wg2 = (const float*)d_in[18];
    const float* bg2 = (const float*)d_in[19];
    const float* Wmu = (const float*)d_in[20];
    const float* bmu = (const float*)d_in[21];
    const float* Wlv = (const float*)d_in[22];
    const float* blv = (const float*)d_in[23];
    float* out = (float*)d_out;

    // ---- workspace carve ----
    float* ws = (float*)d_ws;
    float* bufA  = ws;                                    // N*D3 feat buffer
    float* bufB  = bufA + (size_t)N_NODES * D3;           // N*D3 h buffer
    float* el    = bufB + (size_t)N_NODES * D3;           // N*4
    float* er    = el + N_NODES * NH;                     // N*4
    float* rden  = er + N_NODES * NH;                     // N*4
    float* csr_e = rden + N_NODES * NH;                   // E*4
    float* gate  = csr_e + (size_t)N_EDGES * NH;          // N
    float* anorm = gate + N_NODES;                        // N
    int* ip      = (int*)(anorm + N_NODES);
    int* deg     = ip;                                    // N
    int* rowptr  = deg + N_NODES;                         // N+1
    int* pos     = rowptr + N_NODES + 1;                  // N
    int* csr_src = pos + N_NODES;                         // E
    int* bsum    = csr_src + N_EDGES;                     // 64
    int* boff    = bsum + 64;                             // 64
    int* gptr    = boff + 64;                             // G+1
    // pooling-phase aliases into bufA (free after layer-3 aggregate)
    float* gh    = bufA;                                  // N*HIDG
    float* gemb  = gh + (size_t)N_NODES * HIDG;           // G*D3

    // ---- CSR build ----
    constexpr int NBLK = (N_NODES + SCAN_B - 1) / SCAN_B;   // 40
    zero_int<<<dim3((N_NODES + 255) / 256), dim3(256), 0, stream>>>(deg, N_NODES);
    count_deg<<<dim3((N_EDGES + 255) / 256), dim3(256), 0, stream>>>(dst, deg);
    scan1<<<dim3(NBLK), dim3(SCAN_B), 0, stream>>>(deg, rowptr, bsum);
    scan2<<<dim3(1), dim3(64), 0, stream>>>(bsum, boff, NBLK);
    scan3<<<dim3(NBLK), dim3(SCAN_B), 0, stream>>>(rowptr, boff, pos);
    fill_csr<<<dim3((N_EDGES + 255) / 256), dim3(256), 0, stream>>>(src, dst, pos, csr_src);
    gptr_kernel<<<dim3(1), dim3(256), 0, stream>>>(gid, gptr);

    auto gat = [&](const float* X, const float* W, const float* al, const float* ar,
                   const float* b, float* F, float* R, int K, int O, int D) {
        dim3 gg(D / 128, (N_NODES + 127) / 128);
        gemm128<false, false><<<gg, dim3(256), 0, stream>>>(X, W, nullptr, F, N_NODES, D, K);
        attn_lr<<<dim3(N_NODES), dim3(256), 0, stream>>>(F, al, ar, el, er, O);
        attn_softmax<<<dim3(N_NODES), dim3(64), 0, stream>>>(el, er, rowptr, csr_src, csr_e, rden);
        if (D == 256)
            aggregate<1, 6><<<dim3(N_NODES), dim3(256), 0, stream>>>(F, csr_e, rden, rowptr, csr_src, b, R, D);
        else if (D == 512)
            aggregate<2, 7><<<dim3(N_NODES), dim3(256), 0, stream>>>(F, csr_e, rden, rowptr, csr_src, b, R, D);
        else
            aggregate<4, 8><<<dim3(N_NODES), dim3(256), 0, stream>>>(F, csr_e, rden, rowptr, csr_src, b, R, D);
    };

    // layer 1: X = node_feat -> feat in bufA -> h1 in bufB
    gat(node_feat, W1, al1, ar1, b1, bufA, bufB, F_IN, O1, D1);
    // layer 2
    gat(bufB, W2, al2, ar2, b2, bufA, bufB, D1, O2, D2);
    // layer 3
    gat(bufB, W3, al3, ar3, b3, bufA, bufB, D2, O3, D3);

    // pooling: gh = relu(h3 @ Wg1 + bg1)
    {
        dim3 gg(HIDG / 128, (N_NODES + 127) / 128);
        gemm128<true, true><<<gg, dim3(256), 0, stream>>>(bufB, Wg1, bg1, gh, N_NODES, HIDG, D3);
    }
    gate_kernel<<<dim3(N_NODES), dim3(128), 0, stream>>>(gh, Wg2, bg2, gate);
    gate_stats<<<dim3(N_GRAPH), dim3(64), 0, stream>>>(gate, gptr, anorm);
    pool_gather<<<dim3(D3 / 256, N_GRAPH), dim3(256), 0, stream>>>(bufB, anorm, gptr, gemb);
    heads_kernel<<<dim3(N_GRAPH), dim3(128), 0, stream>>>(gemb, Wmu, bmu, Wlv, blv, out);
}

// Round 3
// 792.059 us; speedup vs baseline: 3.6460x; 1.4252x over previous
//
#include <hip/hip_runtime.h>
#include <math.h>

// ---- problem constants (fixed by the reference) ----
constexpr int N_NODES = 20000;
constexpr int N_EDGES = 320000;
constexpr int N_GRAPH = 200;
constexpr int F_IN    = 128;
constexpr int NH      = 4;
constexpr int O1 = 64,  O2 = 128, O3 = 256;
constexpr int D1 = 256, D2 = 512, D3 = 1024;
constexpr int LAT  = 128;
constexpr int HIDG = 128;
constexpr float NEG_SLOPE = 0.2f;

typedef __attribute__((ext_vector_type(8))) short bf16x8;
typedef __attribute__((ext_vector_type(4))) float f32x4;

// bf16 split: x ~= hi + lo, both RNE-rounded bf16 (stored as raw ushort)
__device__ inline void bsplit(float x, ushort& h, ushort& l) {
    unsigned u = __float_as_uint(x);
    unsigned rh = (u + 0x7fffu + ((u >> 16) & 1u)) & 0xffff0000u;
    h = (ushort)(rh >> 16);
    float res = x - __uint_as_float(rh);
    unsigned u2 = __float_as_uint(res);
    l = (ushort)((u2 + 0x7fffu + ((u2 >> 16) & 1u)) >> 16);
}
__device__ inline float bf2f(ushort u) { return __uint_as_float(((unsigned)u) << 16); }

// ================= CSR build =================
__global__ void zero_int(int* __restrict__ p, int n) {
    int i = blockIdx.x * blockDim.x + threadIdx.x;
    if (i < n) p[i] = 0;
}

__global__ void count_deg(const int* __restrict__ dst, int* __restrict__ deg) {
    int e = blockIdx.x * blockDim.x + threadIdx.x;
    if (e < N_EDGES) atomicAdd(&deg[dst[e]], 1);
}

constexpr int SCAN_B = 512;
__global__ __launch_bounds__(SCAN_B)
void scan1(const int* __restrict__ deg, int* __restrict__ rowptr, int* __restrict__ bsum) {
    __shared__ int s[SCAN_B];
    int tid = threadIdx.x;
    int i = blockIdx.x * SCAN_B + tid;
    int v = (i < N_NODES) ? deg[i] : 0;
    s[tid] = v;
    __syncthreads();
    for (int off = 1; off < SCAN_B; off <<= 1) {
        int add = (tid >= off) ? s[tid - off] : 0;
        __syncthreads();
        s[tid] += add;
        __syncthreads();
    }
    if (i < N_NODES) rowptr[i] = s[tid] - v;
    if (tid == SCAN_B - 1) bsum[blockIdx.x] = s[tid];
}

__global__ void scan2(const int* __restrict__ bsum, int* __restrict__ boff, int nblk) {
    if (threadIdx.x == 0 && blockIdx.x == 0) {
        int run = 0;
        for (int b = 0; b < nblk; ++b) { boff[b] = run; run += bsum[b]; }
    }
}

__global__ __launch_bounds__(SCAN_B)
void scan3(int* __restrict__ rowptr, const int* __restrict__ boff, int* __restrict__ pos) {
    int i = blockIdx.x * SCAN_B + threadIdx.x;
    if (i < N_NODES) {
        int v = rowptr[i] + boff[blockIdx.x];
        rowptr[i] = v;
        pos[i] = v;
    }
    if (i == 0) rowptr[N_NODES] = N_EDGES;
}

__global__ void fill_csr(const int* __restrict__ src, const int* __restrict__ dst,
                         int* __restrict__ pos, int* __restrict__ csr_src) {
    int e = blockIdx.x * blockDim.x + threadIdx.x;
    if (e >= N_EDGES) return;
    int slot = atomicAdd(&pos[dst[e]], 1);
    csr_src[slot] = src[e];
}

__global__ void gptr_kernel(const int* __restrict__ gid, int* __restrict__ gptr) {
    int g = blockIdx.x * blockDim.x + threadIdx.x;
    if (g > N_GRAPH) return;
    int lo = 0, hi = N_NODES;
    while (lo < hi) { int mid = (lo + hi) >> 1; if (gid[mid] < g) lo = mid + 1; else hi = mid; }
    gptr[g] = lo;
}

// ================= conversion kernels =================
// X[M][K] fp32 -> S[M][2K] bf16 (hi | lo)
__global__ void split_x(const float* __restrict__ X, ushort* __restrict__ S, int M, int K) {
    int i = blockIdx.x * 256 + threadIdx.x;
    int total = (M * K) >> 2;
    if (i >= total) return;
    int e0 = i << 2;
    int m = e0 / K, k = e0 % K;
    float4 v = *(const float4*)&X[(size_t)m * K + k];
    ushort h[4], l[4];
    bsplit(v.x, h[0], l[0]); bsplit(v.y, h[1], l[1]);
    bsplit(v.z, h[2], l[2]); bsplit(v.w, h[3], l[3]);
    uint2 hp, lp;
    hp.x = (unsigned)h[0] | ((unsigned)h[1] << 16);
    hp.y = (unsigned)h[2] | ((unsigned)h[3] << 16);
    lp.x = (unsigned)l[0] | ((unsigned)l[1] << 16);
    lp.y = (unsigned)l[2] | ((unsigned)l[3] << 16);
    *(uint2*)&S[(size_t)m * 2 * K + k] = hp;
    *(uint2*)&S[(size_t)m * 2 * K + K + k] = lp;
}

// W[K][N] fp32 -> Bt[N][2K] bf16 (hi | lo), transposed
__global__ __launch_bounds__(256)
void split_wt(const float* __restrict__ W, ushort* __restrict__ Bt, int K, int N) {
    __shared__ float t[32][33];
    int n0 = blockIdx.x * 32, k0 = blockIdx.y * 32;
    int tx = threadIdx.x, ty = threadIdx.y;   // 32 x 8
    for (int j = 0; j < 32; j += 8)
        t[ty + j][tx] = W[(size_t)(k0 + ty + j) * N + n0 + tx];
    __syncthreads();
    for (int j = 0; j < 32; j += 8) {
        float v = t[tx][ty + j];              // = W[k0+tx][n0+ty+j]
        int n = n0 + ty + j, k = k0 + tx;
        ushort h, l;
        bsplit(v, h, l);
        Bt[(size_t)n * 2 * K + k] = h;
        Bt[(size_t)n * 2 * K + K + k] = l;
    }
}

// ================= bf16x3 MFMA GEMM =================
// C[M][N] = A[M][K] @ B[K][N] in fp32-accuracy via 3-term bf16 split.
// Asp: [M][2K] bf16 (hi|lo rows of A). Bt: [N][2K] bf16 (hi|lo of B^T).
// 128x128 tile, BK=64, 4 waves, 16x16x32 MFMA, global_load_lds + XOR swizzle.
#define GLOAD_LDS16(g, s) \
    __builtin_amdgcn_global_load_lds((const __attribute__((address_space(1))) void*)(g), \
                                     (__attribute__((address_space(3))) void*)(s), 16, 0, 0)

template<bool BIAS, bool RELU>
__global__ __launch_bounds__(256)
void gemm_mfma(const ushort* __restrict__ Asp, const ushort* __restrict__ Bt,
               const float* __restrict__ bias, float* __restrict__ C,
               int M, int N, int K, int ntn) {
    __shared__ __align__(16) ushort Asb[128 * 64];
    __shared__ __align__(16) ushort Bsb[128 * 64];

    // m204 bijective XCD swizzle
    const int nwg = gridDim.x;
    int bid = blockIdx.x;
    int q = nwg >> 3, r = nwg & 7;
    int xcd = bid & 7, local = bid >> 3;
    int wg = (xcd < r) ? (xcd * (q + 1) + local) : (r * (q + 1) + (xcd - r) * q + local);
    const int tm = wg / ntn, tn = wg % ntn;

    const int tid = threadIdx.x;
    const int w = tid >> 6, l = tid & 63;
    const int wr = w >> 1, wc = w & 1;
    const size_t sA = 2 * (size_t)K;

    // staging coords: lane l writes LDS bytes [chunk + l*16); logical col pre-swizzled
    const int ld8 = l >> 3;                   // row within 8-row chunk
    const int stg_col = ((l & 7) ^ ld8) << 3; // ushort offset of this lane's 16B
    // reader coords
    const int r15 = l & 15, kq = l >> 4;
    const int swz = (l & 7) << 4;             // byte XOR for ds_read

    f32x4 acc[4][4];
    #pragma unroll
    for (int m = 0; m < 4; ++m)
        #pragma unroll
        for (int n = 0; n < 4; ++n)
            acc[m][n] = 0.f;

    for (int seg = 0; seg < 3; ++seg) {
        const ushort* Aseg = Asp + (seg == 1 ? K : 0);
        const ushort* Bseg = Bt + (seg == 2 ? K : 0);
        for (int k0 = 0; k0 < K; k0 += 64) {
            // ---- stage A,B tiles (each wave: 4 chunks of 8 rows each) ----
            #pragma unroll
            for (int i = 0; i < 4; ++i) {
                int r0 = w * 32 + i * 8;
                int garow = tm * 128 + r0 + ld8;
                if (garow > M - 1) garow = M - 1;
                const ushort* ga = Aseg + (size_t)garow * sA + k0 + stg_col;
                GLOAD_LDS16(ga, &Asb[r0 * 64]);
                int gbrow = tn * 128 + r0 + ld8;
                const ushort* gb = Bseg + (size_t)gbrow * sA + k0 + stg_col;
                GLOAD_LDS16(gb, &Bsb[r0 * 64]);
            }
            asm volatile("s_waitcnt vmcnt(0)");
            __syncthreads();
            // ---- compute: 2 ks x 4m x 4n MFMA ----
            #pragma unroll
            for (int ks = 0; ks < 2; ++ks) {
                bf16x8 af[4], bf[4];
                const int kbyte = (ks * 64 + kq * 16) ^ swz;
                #pragma unroll
                for (int m = 0; m < 4; ++m) {
                    int row = wr * 64 + m * 16 + r15;
                    af[m] = *(const bf16x8*)((const char*)Asb + row * 128 + kbyte);
                }
                #pragma unroll
                for (int n = 0; n < 4; ++n) {
                    int row = wc * 64 + n * 16 + r15;
                    bf[n] = *(const bf16x8*)((const char*)Bsb + row * 128 + kbyte);
                }
                #pragma unroll
                for (int m = 0; m < 4; ++m)
                    #pragma unroll
                    for (int n = 0; n < 4; ++n)
                        acc[m][n] = __builtin_amdgcn_mfma_f32_16x16x32_bf16(af[m], bf[n], acc[m][n], 0, 0, 0);
            }
            __syncthreads();
        }
    }

    // ---- epilogue ----
    #pragma unroll
    for (int m = 0; m < 4; ++m) {
        #pragma unroll
        for (int n = 0; n < 4; ++n) {
            #pragma unroll
            for (int j = 0; j < 4; ++j) {
                int row = tm * 128 + wr * 64 + m * 16 + kq * 4 + j;
                int col = tn * 128 + wc * 64 + n * 16 + r15;
                if (row < M) {
                    float v = acc[m][n][j];
                    if (BIAS) v += bias[col];
                    if (RELU) v = fmaxf(v, 0.f);
                    C[(size_t)row * N + col] = v;
                }
            }
        }
    }
}

// ================= per-node attention halves =================
__global__ __launch_bounds__(256)
void attn_lr(const float* __restrict__ feat, const float* __restrict__ al,
             const float* __restrict__ ar, float* __restrict__ el,
             float* __restrict__ er, int O) {
    int n = blockIdx.x;
    int h = threadIdx.x >> 6;
    int lane = threadIdx.x & 63;
    const float* fr = feat + (size_t)n * (NH * O) + h * O;
    float sl = 0.f, sr = 0.f;
    for (int o = lane; o < O; o += 64) {
        float f = fr[o];
        sl += f * al[h * O + o];
        sr += f * ar[h * O + o];
    }
    #pragma unroll
    for (int off = 32; off; off >>= 1) {
        sl += __shfl_down(sl, off);
        sr += __shfl_down(sr, off);
    }
    if (lane == 0) {
        el[n * NH + h] = sl;
        er[n * NH + h] = sr;
    }
}

// ================= per-dst edge softmax over CSR =================
__global__ __launch_bounds__(64)
void attn_softmax(const float* __restrict__ el, const float* __restrict__ er,
                  const int* __restrict__ rowptr, const int* __restrict__ csr_src,
                  float* __restrict__ csr_e, float* __restrict__ rden) {
    int d = blockIdx.x;
    int lane = threadIdx.x;
    int base = rowptr[d], end = rowptr[d + 1];
    float erd[NH];
    #pragma unroll
    for (int h = 0; h < NH; ++h) erd[h] = er[d * NH + h];

    float mx[NH] = {-INFINITY, -INFINITY, -INFINITY, -INFINITY};
    for (int s = base + lane; s < end; s += 64) {
        int sn = csr_src[s];
        #pragma unroll
        for (int h = 0; h < NH; ++h) {
            float v = el[sn * NH + h] + erd[h];
            v = (v >= 0.f) ? v : NEG_SLOPE * v;
            csr_e[s * NH + h] = v;
            mx[h] = fmaxf(mx[h], v);
        }
    }
    #pragma unroll
    for (int h = 0; h < NH; ++h)
        #pragma unroll
        for (int off = 32; off; off >>= 1)
            mx[h] = fmaxf(mx[h], __shfl_xor(mx[h], off));

    float sm[NH] = {0.f, 0.f, 0.f, 0.f};
    for (int s = base + lane; s < end; s += 64) {
        #pragma unroll
        for (int h = 0; h < NH; ++h) {
            float ex = expf(csr_e[s * NH + h] - mx[h]);
            csr_e[s * NH + h] = ex;
            sm[h] += ex;
        }
    }
    #pragma unroll
    for (int h = 0; h < NH; ++h)
        #pragma unroll
        for (int off = 32; off; off >>= 1)
            sm[h] += __shfl_xor(sm[h], off);

    if (lane == 0) {
        #pragma unroll
        for (int h = 0; h < NH; ++h)
            rden[d * NH + h] = 1.f / fmaxf(sm[h], 1e-9f);
    }
}

// ================= gather aggregation, fused bf16-split output =================
// Ssp[d][2D]: hi|lo of h = elu((sum ex*feat[src])*rden + bias)
template<int REGS, int OSHIFT>
__global__ __launch_bounds__(256)
void aggregate(const float* __restrict__ feat, const float* __restrict__ csr_e,
               const float* __restrict__ rden, const int* __restrict__ rowptr,
               const int* __restrict__ csr_src, const float* __restrict__ bias,
               ushort* __restrict__ Ssp, int D) {
    int d = blockIdx.x;
    int t = threadIdx.x;
    int base = rowptr[d], end = rowptr[d + 1];
    const int col0 = t * REGS;
    const int h = col0 >> OSHIFT;

    float acc[REGS];
    #pragma unroll
    for (int k = 0; k < REGS; ++k) acc[k] = 0.f;

    for (int s = base; s < end; ++s) {
        int sn = csr_src[s];
        float a = csr_e[s * NH + h];
        const float* fr = feat + (size_t)sn * D + col0;
        if (REGS == 4) {
            float4 f = *(const float4*)fr;
            acc[0] += f.x * a; acc[1] += f.y * a; acc[2] += f.z * a; acc[3] += f.w * a;
        } else if (REGS == 2) {
            float2 f = *(const float2*)fr;
            acc[0] += f.x * a; acc[1] += f.y * a;
        } else {
            acc[0] += fr[0] * a;
        }
    }

    float rd = rden[d * NH + h];
    ushort hh[REGS], ll[REGS];
    #pragma unroll
    for (int k = 0; k < REGS; ++k) {
        float v = acc[k] * rd + bias[col0 + k];
        v = (v > 0.f) ? v : expm1f(v);
        bsplit(v, hh[k], ll[k]);
    }
    ushort* hrow = Ssp + (size_t)d * 2 * D;
    #pragma unroll
    for (int k = 0; k < REGS; ++k) {
        hrow[col0 + k] = hh[k];
        hrow[D + col0 + k] = ll[k];
    }
}

// ================= gate scalar =================
__global__ __launch_bounds__(128)
void gate_kernel(const float* __restrict__ gh, const float* __restrict__ Wg2,
                 const float* __restrict__ bg2, float* __restrict__ gate) {
    int n = blockIdx.x;
    int t = threadIdx.x;
    __shared__ float red[128];
    red[t] = gh[(size_t)n * HIDG + t] * Wg2[t];
    __syncthreads();
    for (int s = 64; s; s >>= 1) {
        if (t < s) red[t] += red[t + s];
        __syncthreads();
    }
    if (t == 0) gate[n] = red[0] + bg2[0];
}

__global__ __launch_bounds__(64)
void gate_stats(const float* __restrict__ gate, const int* __restrict__ gptr,
                float* __restrict__ anorm) {
    int g = blockIdx.x;
    int lane = threadIdx.x;
    int s = gptr[g], e = gptr[g + 1];
    float m = -INFINITY;
    for (int n = s + lane; n < e; n += 64) m = fmaxf(m, gate[n]);
    #pragma unroll
    for (int off = 32; off; off >>= 1) m = fmaxf(m, __shfl_xor(m, off));
    float sum = 0.f;
    for (int n = s + lane; n < e; n += 64) sum += expf(gate[n] - m);
    #pragma unroll
    for (int off = 32; off; off >>= 1) sum += __shfl_xor(sum, off);
    float inv = 1.f / fmaxf(sum, 1e-9f);
    for (int n = s + lane; n < e; n += 64) anorm[n] = expf(gate[n] - m) * inv;
}

// gemb[g] = sum_n anorm[n] * h3[n]  (h3 read from split bf16)
__global__ __launch_bounds__(256)
void pool_gather(const ushort* __restrict__ h3sp, const float* __restrict__ anorm,
                 const int* __restrict__ gptr, float* __restrict__ gemb) {
    int g = blockIdx.y;
    int col = blockIdx.x * 256 + threadIdx.x;
    float acc = 0.f;
    int s = gptr[g], e = gptr[g + 1];
    for (int n = s; n < e; ++n) {
        const ushort* row = h3sp + (size_t)n * 2 * D3;
        acc += anorm[n] * (bf2f(row[col]) + bf2f(row[D3 + col]));
    }
    gemb[(size_t)g * D3 + col] = acc;
}

// ================= heads =================
__global__ __launch_bounds__(128)
void heads_kernel(const float* __restrict__ gemb, const float* __restrict__ Wmu,
                  const float* __restrict__ bmu, const float* __restrict__ Wlv,
                  const float* __restrict__ blv, float* __restrict__ out) {
    int g = blockIdx.x;
    int j = threadIdx.x;
    __shared__ float e[D3];
    for (int k = threadIdx.x; k < D3; k += 128) e[k] = gemb[(size_t)g * D3 + k];
    __syncthreads();
    float smu = 0.f, slv = 0.f;
    for (int k = 0; k < D3; ++k) {
        float v = e[k];
        smu += v * Wmu[k * LAT + j];
        slv += v * Wlv[k * LAT + j];
    }
    out[g * LAT + j] = smu + bmu[j];
    out[N_GRAPH * LAT + g * LAT + j] = slv + blv[j];
}

// ================= host launch =================
extern "C" void kernel_launch(void* const* d_in, const int* in_sizes, int n_in,
                              void* d_out, int out_size, void* d_ws, size_t ws_size,
                              hipStream_t stream) {
    const float* node_feat = (const float*)d_in[0];
    const int*   src = (const int*)d_in[1];
    const int*   dst = (const int*)d_in[2];
    const int*   gid = (const int*)d_in[3];
    const float* W1  = (const float*)d_in[4];
    const float* al1 = (const float*)d_in[5];
    const float* ar1 = (const float*)d_in[6];
    const float* b1  = (const float*)d_in[7];
    const float* W2  = (const float*)d_in[8];
    const float* al2 = (const float*)d_in[9];
    const float* ar2 = (const float*)d_in[10];
    const float* b2  = (const float*)d_in[11];
    const float* W3  = (const float*)d_in[12];
    const float* al3 = (const float*)d_in[13];
    const float* ar3 = (const float*)d_in[14];
    const float* b3  = (const float*)d_in[15];
    const float* Wg1 = (const float*)d_in[16];
    const float* bg1 = (const float*)d_in[17];
    const float* Wg2 = (const float*)d_in[18];
    const float* bg2 = (const float*)d_in[19];
    const float* Wmu = (const float*)d_in[20];
    const float* bmu = (const float*)d_in[21];
    const float* Wlv = (const float*)d_in[22];
    const float* blv = (const float*)d_in[23];
    float* out = (float*)d_out;

    // ---- workspace carve ----
    char* wsb = (char*)d_ws;
    float* bufA   = (float*)wsb;                                   // N*D3 f32 (feat)
    wsb += (size_t)N_NODES * D3 * 4;
    ushort* Xsp   = (ushort*)wsb;                                  // N*2048 bf16 (split acts)
    wsb += (size_t)N_NODES * 2048 * 2;
    ushort* Bt1   = (ushort*)wsb; wsb += (size_t)D1 * 2 * F_IN * 2;   // [256][256]
    ushort* Bt2   = (ushort*)wsb; wsb += (size_t)D2 * 2 * D1 * 2;     // [512][512]
    ushort* Bt3   = (ushort*)wsb; wsb += (size_t)D3 * 2 * D2 * 2;     // [1024][1024]
    ushort* Btg   = (ushort*)wsb; wsb += (size_t)HIDG * 2 * D3 * 2;   // [128][2048]
    float* el     = (float*)wsb;  wsb += (size_t)N_NODES * NH * 4;
    float* er     = (float*)wsb;  wsb += (size_t)N_NODES * NH * 4;
    float* rden   = (float*)wsb;  wsb += (size_t)N_NODES * NH * 4;
    float* csr_e  = (float*)wsb;  wsb += (size_t)N_EDGES * NH * 4;
    float* gate   = (float*)wsb;  wsb += (size_t)N_NODES * 4;
    float* anorm  = (float*)wsb;  wsb += (size_t)N_NODES * 4;
    int* deg      = (int*)wsb;    wsb += (size_t)N_NODES * 4;
    int* rowptr   = (int*)wsb;    wsb += (size_t)(N_NODES + 1) * 4;
    int* pos      = (int*)wsb;    wsb += (size_t)N_NODES * 4;
    int* csr_src  = (int*)wsb;    wsb += (size_t)N_EDGES * 4;
    int* bsum     = (int*)wsb;    wsb += 64 * 4;
    int* boff     = (int*)wsb;    wsb += 64 * 4;
    int* gptr     = (int*)wsb;    wsb += (size_t)(N_GRAPH + 1) * 4;
    // pooling-phase aliases into bufA (feat3 dead after aggregate3)
    float* gh     = bufA;                                          // N*HIDG f32
    float* gemb   = gh + (size_t)N_NODES * HIDG;                   // G*D3 f32

    // ---- CSR build ----
    constexpr int NBLK = (N_NODES + SCAN_B - 1) / SCAN_B;
    zero_int<<<dim3((N_NODES + 255) / 256), dim3(256), 0, stream>>>(deg, N_NODES);
    count_deg<<<dim3((N_EDGES + 255) / 256), dim3(256), 0, stream>>>(dst, deg);
    scan1<<<dim3(NBLK), dim3(SCAN_B), 0, stream>>>(deg, rowptr, bsum);
    scan2<<<dim3(1), dim3(64), 0, stream>>>(bsum, boff, NBLK);
    scan3<<<dim3(NBLK), dim3(SCAN_B), 0, stream>>>(rowptr, boff, pos);
    fill_csr<<<dim3((N_EDGES + 255) / 256), dim3(256), 0, stream>>>(src, dst, pos, csr_src);
    gptr_kernel<<<dim3(1), dim3(256), 0, stream>>>(gid, gptr);

    // ---- weight splits (transposed) ----
    split_wt<<<dim3(D1 / 32, F_IN / 32), dim3(32, 8), 0, stream>>>(W1, Bt1, F_IN, D1);
    split_wt<<<dim3(D2 / 32, D1 / 32),   dim3(32, 8), 0, stream>>>(W2, Bt2, D1, D2);
    split_wt<<<dim3(D3 / 32, D2 / 32),   dim3(32, 8), 0, stream>>>(W3, Bt3, D2, D3);
    split_wt<<<dim3(HIDG / 32, D3 / 32), dim3(32, 8), 0, stream>>>(Wg1, Btg, D3, HIDG);

    // ---- layer-1 input split (into front of Xsp; dead before aggregate1 writes) ----
    split_x<<<dim3((N_NODES * F_IN / 4 + 255) / 256), dim3(256), 0, stream>>>(node_feat, Xsp, N_NODES, F_IN);

    auto gat = [&](const ushort* Bt, const float* al, const float* ar, const float* b,
                   int K, int O, int D) {
        int ntn = D / 128;
        int nwg = 157 * ntn;
        gemm_mfma<false, false><<<dim3(nwg), dim3(256), 0, stream>>>(Xsp, Bt, nullptr, bufA, N_NODES, D, K, ntn);
        attn_lr<<<dim3(N_NODES), dim3(256), 0, stream>>>(bufA, al, ar, el, er, O);
        attn_softmax<<<dim3(N_NODES), dim3(64), 0, stream>>>(el, er, rowptr, csr_src, csr_e, rden);
        if (D == 256)
            aggregate<1, 6><<<dim3(N_NODES), dim3(256), 0, stream>>>(bufA, csr_e, rden, rowptr, csr_src, b, Xsp, D);
        else if (D == 512)
            aggregate<2, 7><<<dim3(N_NODES), dim3(256), 0, stream>>>(bufA, csr_e, rden, rowptr, csr_src, b, Xsp, D);
        else
            aggregate<4, 8><<<dim3(N_NODES), dim3(256), 0, stream>>>(bufA, csr_e, rden, rowptr, csr_src, b, Xsp, D);
    };

    gat(Bt1, al1, ar1, b1, F_IN, O1, D1);   // h1 split in Xsp [N][512]
    gat(Bt2, al2, ar2, b2, D1, O2, D2);     // h2 split in Xsp [N][1024]
    gat(Bt3, al3, ar3, b3, D2, O3, D3);     // h3 split in Xsp [N][2048]

    // pooling: gh = relu(h3 @ Wg1 + bg1)
    gemm_mfma<true, true><<<dim3(157), dim3(256), 0, stream>>>(Xsp, Btg, bg1, gh, N_NODES, HIDG, D3, 1);
    gate_kernel<<<dim3(N_NODES), dim3(128), 0, stream>>>(gh, Wg2, bg2, gate);
    gate_stats<<<dim3(N_GRAPH), dim3(64), 0, stream>>>(gate, gptr, anorm);
    pool_gather<<<dim3(D3 / 256, N_GRAPH), dim3(256), 0, stream>>>(Xsp, anorm, gptr, gemb);
    heads_kernel<<<dim3(N_GRAPH), dim3(128), 0, stream>>>(gemb, Wmu, bmu, Wlv, blv, out);
}

// Round 4
// 654.229 us; speedup vs baseline: 4.4141x; 1.2107x over previous
//
#include <hip/hip_runtime.h>
#include <math.h>

// ---- problem constants (fixed by the reference) ----
constexpr int N_NODES = 20000;
constexpr int N_EDGES = 320000;
constexpr int N_GRAPH = 200;
constexpr int F_IN    = 128;
constexpr int NH      = 4;
constexpr int O1 = 64,  O2 = 128, O3 = 256;
constexpr int D1 = 256, D2 = 512, D3 = 1024;
constexpr int LAT  = 128;
constexpr int HIDG = 128;
constexpr float NEG_SLOPE = 0.2f;

typedef __attribute__((ext_vector_type(8))) short bf16x8;
typedef __attribute__((ext_vector_type(4))) float f32x4;

// bf16 split: x ~= hi + lo, both RNE-rounded bf16 (stored as raw ushort)
__device__ inline void bsplit(float x, ushort& h, ushort& l) {
    unsigned u = __float_as_uint(x);
    unsigned rh = (u + 0x7fffu + ((u >> 16) & 1u)) & 0xffff0000u;
    h = (ushort)(rh >> 16);
    float res = x - __uint_as_float(rh);
    unsigned u2 = __float_as_uint(res);
    l = (ushort)((u2 + 0x7fffu + ((u2 >> 16) & 1u)) >> 16);
}
__device__ inline ushort f2bf(float x) {
    unsigned u = __float_as_uint(x);
    return (ushort)((u + 0x7fffu + ((u >> 16) & 1u)) >> 16);
}
__device__ inline float bf2f(ushort u) { return __uint_as_float(((unsigned)u) << 16); }

// ================= CSR build =================
__global__ void zero_int(int* __restrict__ p, int n) {
    int i = blockIdx.x * blockDim.x + threadIdx.x;
    if (i < n) p[i] = 0;
}

__global__ void count_deg(const int* __restrict__ dst, int* __restrict__ deg) {
    int e = blockIdx.x * blockDim.x + threadIdx.x;
    if (e < N_EDGES) atomicAdd(&deg[dst[e]], 1);
}

constexpr int SCAN_B = 512;
__global__ __launch_bounds__(SCAN_B)
void scan1(const int* __restrict__ deg, int* __restrict__ rowptr, int* __restrict__ bsum) {
    __shared__ int s[SCAN_B];
    int tid = threadIdx.x;
    int i = blockIdx.x * SCAN_B + tid;
    int v = (i < N_NODES) ? deg[i] : 0;
    s[tid] = v;
    __syncthreads();
    for (int off = 1; off < SCAN_B; off <<= 1) {
        int add = (tid >= off) ? s[tid - off] : 0;
        __syncthreads();
        s[tid] += add;
        __syncthreads();
    }
    if (i < N_NODES) rowptr[i] = s[tid] - v;
    if (tid == SCAN_B - 1) bsum[blockIdx.x] = s[tid];
}

__global__ void scan2(const int* __restrict__ bsum, int* __restrict__ boff, int nblk) {
    if (threadIdx.x == 0 && blockIdx.x == 0) {
        int run = 0;
        for (int b = 0; b < nblk; ++b) { boff[b] = run; run += bsum[b]; }
    }
}

__global__ __launch_bounds__(SCAN_B)
void scan3(int* __restrict__ rowptr, const int* __restrict__ boff, int* __restrict__ pos) {
    int i = blockIdx.x * SCAN_B + threadIdx.x;
    if (i < N_NODES) {
        int v = rowptr[i] + boff[blockIdx.x];
        rowptr[i] = v;
        pos[i] = v;
    }
    if (i == 0) rowptr[N_NODES] = N_EDGES;
}

__global__ void fill_csr(const int* __restrict__ src, const int* __restrict__ dst,
                         int* __restrict__ pos, int* __restrict__ csr_src) {
    int e = blockIdx.x * blockDim.x + threadIdx.x;
    if (e >= N_EDGES) return;
    int slot = atomicAdd(&pos[dst[e]], 1);
    csr_src[slot] = src[e];
}

__global__ void gptr_kernel(const int* __restrict__ gid, int* __restrict__ gptr) {
    int g = blockIdx.x * blockDim.x + threadIdx.x;
    if (g > N_GRAPH) return;
    int lo = 0, hi = N_NODES;
    while (lo < hi) { int mid = (lo + hi) >> 1; if (gid[mid] < g) lo = mid + 1; else hi = mid; }
    gptr[g] = lo;
}

// ================= conversion kernels =================
__global__ void split_x(const float* __restrict__ X, ushort* __restrict__ S, int M, int K) {
    int i = blockIdx.x * 256 + threadIdx.x;
    int total = (M * K) >> 2;
    if (i >= total) return;
    int e0 = i << 2;
    int m = e0 / K, k = e0 % K;
    float4 v = *(const float4*)&X[(size_t)m * K + k];
    ushort h[4], l[4];
    bsplit(v.x, h[0], l[0]); bsplit(v.y, h[1], l[1]);
    bsplit(v.z, h[2], l[2]); bsplit(v.w, h[3], l[3]);
    uint2 hp, lp;
    hp.x = (unsigned)h[0] | ((unsigned)h[1] << 16);
    hp.y = (unsigned)h[2] | ((unsigned)h[3] << 16);
    lp.x = (unsigned)l[0] | ((unsigned)l[1] << 16);
    lp.y = (unsigned)l[2] | ((unsigned)l[3] << 16);
    *(uint2*)&S[(size_t)m * 2 * K + k] = hp;
    *(uint2*)&S[(size_t)m * 2 * K + K + k] = lp;
}

__global__ __launch_bounds__(256)
void split_wt(const float* __restrict__ W, ushort* __restrict__ Bt, int K, int N) {
    __shared__ float t[32][33];
    int n0 = blockIdx.x * 32, k0 = blockIdx.y * 32;
    int tx = threadIdx.x, ty = threadIdx.y;   // 32 x 8
    for (int j = 0; j < 32; j += 8)
        t[ty + j][tx] = W[(size_t)(k0 + ty + j) * N + n0 + tx];
    __syncthreads();
    for (int j = 0; j < 32; j += 8) {
        float v = t[tx][ty + j];
        int n = n0 + ty + j, k = k0 + tx;
        ushort h, l;
        bsplit(v, h, l);
        Bt[(size_t)n * 2 * K + k] = h;
        Bt[(size_t)n * 2 * K + K + k] = l;
    }
}

// ================= bf16x3 MFMA GEMM =================
#define GLOAD_LDS16(g, s) \
    __builtin_amdgcn_global_load_lds((const __attribute__((address_space(1))) void*)(g), \
                                     (__attribute__((address_space(3))) void*)(s), 16, 0, 0)

template<bool BIAS, bool RELU, bool OBF16>
__global__ __launch_bounds__(256)
void gemm_mfma(const ushort* __restrict__ Asp, const ushort* __restrict__ Bt,
               const float* __restrict__ bias, void* __restrict__ Cout,
               int M, int N, int K, int ntn) {
    __shared__ __align__(16) ushort Asb[128 * 64];
    __shared__ __align__(16) ushort Bsb[128 * 64];

    const int nwg = gridDim.x;
    int bid = blockIdx.x;
    int q = nwg >> 3, r = nwg & 7;
    int xcd = bid & 7, local = bid >> 3;
    int wg = (xcd < r) ? (xcd * (q + 1) + local) : (r * (q + 1) + (xcd - r) * q + local);
    const int tm = wg / ntn, tn = wg % ntn;

    const int tid = threadIdx.x;
    const int w = tid >> 6, l = tid & 63;
    const int wr = w >> 1, wc = w & 1;
    const size_t sA = 2 * (size_t)K;

    const int ld8 = l >> 3;
    const int stg_col = ((l & 7) ^ ld8) << 3;
    const int r15 = l & 15, kq = l >> 4;
    const int swz = (l & 7) << 4;

    f32x4 acc[4][4];
    #pragma unroll
    for (int m = 0; m < 4; ++m)
        #pragma unroll
        for (int n = 0; n < 4; ++n)
            acc[m][n] = 0.f;

    for (int seg = 0; seg < 3; ++seg) {
        const ushort* Aseg = Asp + (seg == 1 ? K : 0);
        const ushort* Bseg = Bt + (seg == 2 ? K : 0);
        for (int k0 = 0; k0 < K; k0 += 64) {
            #pragma unroll
            for (int i = 0; i < 4; ++i) {
                int r0 = w * 32 + i * 8;
                int garow = tm * 128 + r0 + ld8;
                if (garow > M - 1) garow = M - 1;
                const ushort* ga = Aseg + (size_t)garow * sA + k0 + stg_col;
                GLOAD_LDS16(ga, &Asb[r0 * 64]);
                int gbrow = tn * 128 + r0 + ld8;
                const ushort* gb = Bseg + (size_t)gbrow * sA + k0 + stg_col;
                GLOAD_LDS16(gb, &Bsb[r0 * 64]);
            }
            asm volatile("s_waitcnt vmcnt(0)");
            __syncthreads();
            #pragma unroll
            for (int ks = 0; ks < 2; ++ks) {
                bf16x8 af[4], bf[4];
                const int kbyte = (ks * 64 + kq * 16) ^ swz;
                #pragma unroll
                for (int m = 0; m < 4; ++m) {
                    int row = wr * 64 + m * 16 + r15;
                    af[m] = *(const bf16x8*)((const char*)Asb + row * 128 + kbyte);
                }
                #pragma unroll
                for (int n = 0; n < 4; ++n) {
                    int row = wc * 64 + n * 16 + r15;
                    bf[n] = *(const bf16x8*)((const char*)Bsb + row * 128 + kbyte);
                }
                #pragma unroll
                for (int m = 0; m < 4; ++m)
                    #pragma unroll
                    for (int n = 0; n < 4; ++n)
                        acc[m][n] = __builtin_amdgcn_mfma_f32_16x16x32_bf16(af[m], bf[n], acc[m][n], 0, 0, 0);
            }
            __syncthreads();
        }
    }

    #pragma unroll
    for (int m = 0; m < 4; ++m) {
        #pragma unroll
        for (int n = 0; n < 4; ++n) {
            #pragma unroll
            for (int j = 0; j < 4; ++j) {
                int row = tm * 128 + wr * 64 + m * 16 + kq * 4 + j;
                int col = tn * 128 + wc * 64 + n * 16 + r15;
                if (row < M) {
                    float v = acc[m][n][j];
                    if (BIAS) v += bias[col];
                    if (RELU) v = fmaxf(v, 0.f);
                    if (OBF16)
                        ((ushort*)Cout)[(size_t)row * N + col] = f2bf(v);
                    else
                        ((float*)Cout)[(size_t)row * N + col] = v;
                }
            }
        }
    }
}

// ================= per-node attention halves (fp32 feat) =================
__global__ __launch_bounds__(256)
void attn_lr(const float* __restrict__ feat, const float* __restrict__ al,
             const float* __restrict__ ar, float* __restrict__ el,
             float* __restrict__ er, int O) {
    int n = blockIdx.x;
    int h = threadIdx.x >> 6;
    int lane = threadIdx.x & 63;
    const float* fr = feat + (size_t)n * (NH * O) + h * O;
    float sl = 0.f, sr = 0.f;
    for (int o = lane; o < O; o += 64) {
        float f = fr[o];
        sl += f * al[h * O + o];
        sr += f * ar[h * O + o];
    }
    #pragma unroll
    for (int off = 32; off; off >>= 1) {
        sl += __shfl_down(sl, off);
        sr += __shfl_down(sr, off);
    }
    if (lane == 0) {
        el[n * NH + h] = sl;
        er[n * NH + h] = sr;
    }
}

// bf16-plane variant
__global__ __launch_bounds__(256)
void attn_lr_b(const ushort* __restrict__ feat, const float* __restrict__ al,
               const float* __restrict__ ar, float* __restrict__ el,
               float* __restrict__ er, int O) {
    int n = blockIdx.x;
    int h = threadIdx.x >> 6;
    int lane = threadIdx.x & 63;
    const ushort* fr = feat + (size_t)n * (NH * O) + h * O;
    float sl = 0.f, sr = 0.f;
    for (int o = lane; o < O; o += 64) {
        float f = bf2f(fr[o]);
        sl += f * al[h * O + o];
        sr += f * ar[h * O + o];
    }
    #pragma unroll
    for (int off = 32; off; off >>= 1) {
        sl += __shfl_down(sl, off);
        sr += __shfl_down(sr, off);
    }
    if (lane == 0) {
        el[n * NH + h] = sl;
        er[n * NH + h] = sr;
    }
}

// ================= per-dst edge softmax over CSR =================
__global__ __launch_bounds__(64)
void attn_softmax(const float* __restrict__ el, const float* __restrict__ er,
                  const int* __restrict__ rowptr, const int* __restrict__ csr_src,
                  float* __restrict__ csr_e, float* __restrict__ rden) {
    int d = blockIdx.x;
    int lane = threadIdx.x;
    int base = rowptr[d], end = rowptr[d + 1];
    float erd[NH];
    #pragma unroll
    for (int h = 0; h < NH; ++h) erd[h] = er[d * NH + h];

    float mx[NH] = {-INFINITY, -INFINITY, -INFINITY, -INFINITY};
    for (int s = base + lane; s < end; s += 64) {
        int sn = csr_src[s];
        #pragma unroll
        for (int h = 0; h < NH; ++h) {
            float v = el[sn * NH + h] + erd[h];
            v = (v >= 0.f) ? v : NEG_SLOPE * v;
            csr_e[s * NH + h] = v;
            mx[h] = fmaxf(mx[h], v);
        }
    }
    #pragma unroll
    for (int h = 0; h < NH; ++h)
        #pragma unroll
        for (int off = 32; off; off >>= 1)
            mx[h] = fmaxf(mx[h], __shfl_xor(mx[h], off));

    float sm[NH] = {0.f, 0.f, 0.f, 0.f};
    for (int s = base + lane; s < end; s += 64) {
        #pragma unroll
        for (int h = 0; h < NH; ++h) {
            float ex = expf(csr_e[s * NH + h] - mx[h]);
            csr_e[s * NH + h] = ex;
            sm[h] += ex;
        }
    }
    #pragma unroll
    for (int h = 0; h < NH; ++h)
        #pragma unroll
        for (int off = 32; off; off >>= 1)
            sm[h] += __shfl_xor(sm[h], off);

    if (lane == 0) {
        #pragma unroll
        for (int h = 0; h < NH; ++h)
            rden[d * NH + h] = 1.f / fmaxf(sm[h], 1e-9f);
    }
}

// ================= gather aggregation (fp32 feat), split bf16 output =========
template<int REGS, int OSHIFT>
__global__ __launch_bounds__(256)
void aggregate(const float* __restrict__ feat, const float* __restrict__ csr_e,
               const float* __restrict__ rden, const int* __restrict__ rowptr,
               const int* __restrict__ csr_src, const float* __restrict__ bias,
               ushort* __restrict__ Ssp, int D) {
    int d = blockIdx.x;
    int t = threadIdx.x;
    int base = rowptr[d], end = rowptr[d + 1];
    const int col0 = t * REGS;
    const int h = col0 >> OSHIFT;

    float acc[REGS];
    #pragma unroll
    for (int k = 0; k < REGS; ++k) acc[k] = 0.f;

    int s = base;
    for (; s + 1 < end; s += 2) {
        int sn0 = csr_src[s], sn1 = csr_src[s + 1];
        float a0 = csr_e[s * NH + h], a1 = csr_e[(s + 1) * NH + h];
        const float* f0 = feat + (size_t)sn0 * D + col0;
        const float* f1 = feat + (size_t)sn1 * D + col0;
        #pragma unroll
        for (int k = 0; k < REGS; ++k) acc[k] += f0[k] * a0;
        #pragma unroll
        for (int k = 0; k < REGS; ++k) acc[k] += f1[k] * a1;
    }
    if (s < end) {
        int sn = csr_src[s];
        float a = csr_e[s * NH + h];
        const float* fr = feat + (size_t)sn * D + col0;
        #pragma unroll
        for (int k = 0; k < REGS; ++k) acc[k] += fr[k] * a;
    }

    float rd = rden[d * NH + h];
    ushort hh[REGS], ll[REGS];
    #pragma unroll
    for (int k = 0; k < REGS; ++k) {
        float v = acc[k] * rd + bias[col0 + k];
        v = (v > 0.f) ? v : expm1f(v);
        bsplit(v, hh[k], ll[k]);
    }
    ushort* hrow = Ssp + (size_t)d * 2 * D;
    #pragma unroll
    for (int k = 0; k < REGS; ++k) {
        hrow[col0 + k] = hh[k];
        hrow[D + col0 + k] = ll[k];
    }
}

// ================= gather aggregation (bf16 feat plane) =====================
template<int REGS, int OSHIFT>
__global__ __launch_bounds__(256)
void aggregate_b(const ushort* __restrict__ feat, const float* __restrict__ csr_e,
                 const float* __restrict__ rden, const int* __restrict__ rowptr,
                 const int* __restrict__ csr_src, const float* __restrict__ bias,
                 ushort* __restrict__ Ssp, int D) {
    int d = blockIdx.x;
    int t = threadIdx.x;
    int base = rowptr[d], end = rowptr[d + 1];
    const int col0 = t * REGS;
    const int h = col0 >> OSHIFT;

    float acc[REGS];
    #pragma unroll
    for (int k = 0; k < REGS; ++k) acc[k] = 0.f;

    int s = base;
    for (; s + 1 < end; s += 2) {
        int sn0 = csr_src[s], sn1 = csr_src[s + 1];
        float a0 = csr_e[s * NH + h], a1 = csr_e[(s + 1) * NH + h];
        const ushort* f0 = feat + (size_t)sn0 * D + col0;
        const ushort* f1 = feat + (size_t)sn1 * D + col0;
        if (REGS == 4) {
            ushort4 u0 = *(const ushort4*)f0;
            ushort4 u1 = *(const ushort4*)f1;
            acc[0] += bf2f(u0.x) * a0; acc[1] += bf2f(u0.y) * a0;
            acc[2] += bf2f(u0.z) * a0; acc[3] += bf2f(u0.w) * a0;
            acc[0] += bf2f(u1.x) * a1; acc[1] += bf2f(u1.y) * a1;
            acc[2] += bf2f(u1.z) * a1; acc[3] += bf2f(u1.w) * a1;
        } else {
            ushort2 u0 = *(const ushort2*)f0;
            ushort2 u1 = *(const ushort2*)f1;
            acc[0] += bf2f(u0.x) * a0; acc[1] += bf2f(u0.y) * a0;
            acc[0] += bf2f(u1.x) * a1; acc[1] += bf2f(u1.y) * a1;
        }
    }
    if (s < end) {
        int sn = csr_src[s];
        float a = csr_e[s * NH + h];
        const ushort* fr = feat + (size_t)sn * D + col0;
        if (REGS == 4) {
            ushort4 u = *(const ushort4*)fr;
            acc[0] += bf2f(u.x) * a; acc[1] += bf2f(u.y) * a;
            acc[2] += bf2f(u.z) * a; acc[3] += bf2f(u.w) * a;
        } else {
            ushort2 u = *(const ushort2*)fr;
            acc[0] += bf2f(u.x) * a; acc[1] += bf2f(u.y) * a;
        }
    }

    float rd = rden[d * NH + h];
    ushort hh[REGS], ll[REGS];
    #pragma unroll
    for (int k = 0; k < REGS; ++k) {
        float v = acc[k] * rd + bias[col0 + k];
        v = (v > 0.f) ? v : expm1f(v);
        bsplit(v, hh[k], ll[k]);
    }
    ushort* hrow = Ssp + (size_t)d * 2 * D;
    #pragma unroll
    for (int k = 0; k < REGS; ++k) {
        hrow[col0 + k] = hh[k];
        hrow[D + col0 + k] = ll[k];
    }
}

// ================= gate scalar =================
__global__ __launch_bounds__(128)
void gate_kernel(const float* __restrict__ gh, const float* __restrict__ Wg2,
                 const float* __restrict__ bg2, float* __restrict__ gate) {
    int n = blockIdx.x;
    int t = threadIdx.x;
    __shared__ float red[128];
    red[t] = gh[(size_t)n * HIDG + t] * Wg2[t];
    __syncthreads();
    for (int s = 64; s; s >>= 1) {
        if (t < s) red[t] += red[t + s];
        __syncthreads();
    }
    if (t == 0) gate[n] = red[0] + bg2[0];
}

__global__ __launch_bounds__(64)
void gate_stats(const float* __restrict__ gate, const int* __restrict__ gptr,
                float* __restrict__ anorm) {
    int g = blockIdx.x;
    int lane = threadIdx.x;
    int s = gptr[g], e = gptr[g + 1];
    float m = -INFINITY;
    for (int n = s + lane; n < e; n += 64) m = fmaxf(m, gate[n]);
    #pragma unroll
    for (int off = 32; off; off >>= 1) m = fmaxf(m, __shfl_xor(m, off));
    float sum = 0.f;
    for (int n = s + lane; n < e; n += 64) sum += expf(gate[n] - m);
    #pragma unroll
    for (int off = 32; off; off >>= 1) sum += __shfl_xor(sum, off);
    float inv = 1.f / fmaxf(sum, 1e-9f);
    for (int n = s + lane; n < e; n += 64) anorm[n] = expf(gate[n] - m) * inv;
}

// gemb[g] = sum_n anorm[n] * h3[n]  (h3 read from split bf16)
__global__ __launch_bounds__(256)
void pool_gather(const ushort* __restrict__ h3sp, const float* __restrict__ anorm,
                 const int* __restrict__ gptr, float* __restrict__ gemb) {
    int g = blockIdx.y;
    int col = blockIdx.x * 256 + threadIdx.x;
    float acc = 0.f;
    int s = gptr[g], e = gptr[g + 1];
    for (int n = s; n < e; ++n) {
        const ushort* row = h3sp + (size_t)n * 2 * D3;
        acc += anorm[n] * (bf2f(row[col]) + bf2f(row[D3 + col]));
    }
    gemb[(size_t)g * D3 + col] = acc;
}

// ================= heads =================
__global__ __launch_bounds__(128)
void heads_kernel(const float* __restrict__ gemb, const float* __restrict__ Wmu,
                  const float* __restrict__ bmu, const float* __restrict__ Wlv,
                  const float* __restrict__ blv, float* __restrict__ out) {
    int g = blockIdx.x;
    int j = threadIdx.x;
    __shared__ float e[D3];
    for (int k = threadIdx.x; k < D3; k += 128) e[k] = gemb[(size_t)g * D3 + k];
    __syncthreads();
    float smu = 0.f, slv = 0.f;
    for (int k = 0; k < D3; ++k) {
        float v = e[k];
        smu += v * Wmu[k * LAT + j];
        slv += v * Wlv[k * LAT + j];
    }
    out[g * LAT + j] = smu + bmu[j];
    out[N_GRAPH * LAT + g * LAT + j] = slv + blv[j];
}

// ================= host launch =================
extern "C" void kernel_launch(void* const* d_in, const int* in_sizes, int n_in,
                              void* d_out, int out_size, void* d_ws, size_t ws_size,
                              hipStream_t stream) {
    const float* node_feat = (const float*)d_in[0];
    const int*   src = (const int*)d_in[1];
    const int*   dst = (const int*)d_in[2];
    const int*   gid = (const int*)d_in[3];
    const float* W1  = (const float*)d_in[4];
    const float* al1 = (const float*)d_in[5];
    const float* ar1 = (const float*)d_in[6];
    const float* b1  = (const float*)d_in[7];
    const float* W2  = (const float*)d_in[8];
    const float* al2 = (const float*)d_in[9];
    const float* ar2 = (const float*)d_in[10];
    const float* b2  = (const float*)d_in[11];
    const float* W3  = (const float*)d_in[12];
    const float* al3 = (const float*)d_in[13];
    const float* ar3 = (const float*)d_in[14];
    const float* b3  = (const float*)d_in[15];
    const float* Wg1 = (const float*)d_in[16];
    const float* bg1 = (const float*)d_in[17];
    const float* Wg2 = (const float*)d_in[18];
    const float* bg2 = (const float*)d_in[19];
    const float* Wmu = (const float*)d_in[20];
    const float* bmu = (const float*)d_in[21];
    const float* Wlv = (const float*)d_in[22];
    const float* blv = (const float*)d_in[23];
    float* out = (float*)d_out;

    // ---- workspace carve ----
    char* wsb = (char*)d_ws;
    float* bufA   = (float*)wsb;                                   // N*D3 f32 (feat / bf16 plane)
    wsb += (size_t)N_NODES * D3 * 4;
    ushort* Xsp   = (ushort*)wsb;                                  // N*2048 bf16 (split acts)
    wsb += (size_t)N_NODES * 2048 * 2;
    ushort* Bt1   = (ushort*)wsb; wsb += (size_t)D1 * 2 * F_IN * 2;
    ushort* Bt2   = (ushort*)wsb; wsb += (size_t)D2 * 2 * D1 * 2;
    ushort* Bt3   = (ushort*)wsb; wsb += (size_t)D3 * 2 * D2 * 2;
    ushort* Btg   = (ushort*)wsb; wsb += (size_t)HIDG * 2 * D3 * 2;
    float* el     = (float*)wsb;  wsb += (size_t)N_NODES * NH * 4;
    float* er     = (float*)wsb;  wsb += (size_t)N_NODES * NH * 4;
    float* rden   = (float*)wsb;  wsb += (size_t)N_NODES * NH * 4;
    float* csr_e  = (float*)wsb;  wsb += (size_t)N_EDGES * NH * 4;
    float* gate   = (float*)wsb;  wsb += (size_t)N_NODES * 4;
    float* anorm  = (float*)wsb;  wsb += (size_t)N_NODES * 4;
    int* deg      = (int*)wsb;    wsb += (size_t)N_NODES * 4;
    int* rowptr   = (int*)wsb;    wsb += (size_t)(N_NODES + 1) * 4;
    int* pos      = (int*)wsb;    wsb += (size_t)N_NODES * 4;
    int* csr_src  = (int*)wsb;    wsb += (size_t)N_EDGES * 4;
    int* bsum     = (int*)wsb;    wsb += 64 * 4;
    int* boff     = (int*)wsb;    wsb += 64 * 4;
    int* gptr     = (int*)wsb;    wsb += (size_t)(N_GRAPH + 1) * 4;
    ushort* featb = (ushort*)bufA;                                 // bf16 plane alias
    float* gh     = bufA;                                          // pooling-phase alias
    float* gemb   = gh + (size_t)N_NODES * HIDG;

    // ---- CSR build ----
    constexpr int NBLK = (N_NODES + SCAN_B - 1) / SCAN_B;
    zero_int<<<dim3((N_NODES + 255) / 256), dim3(256), 0, stream>>>(deg, N_NODES);
    count_deg<<<dim3((N_EDGES + 255) / 256), dim3(256), 0, stream>>>(dst, deg);
    scan1<<<dim3(NBLK), dim3(SCAN_B), 0, stream>>>(deg, rowptr, bsum);
    scan2<<<dim3(1), dim3(64), 0, stream>>>(bsum, boff, NBLK);
    scan3<<<dim3(NBLK), dim3(SCAN_B), 0, stream>>>(rowptr, boff, pos);
    fill_csr<<<dim3((N_EDGES + 255) / 256), dim3(256), 0, stream>>>(src, dst, pos, csr_src);
    gptr_kernel<<<dim3(1), dim3(256), 0, stream>>>(gid, gptr);

    // ---- weight splits (transposed) ----
    split_wt<<<dim3(D1 / 32, F_IN / 32), dim3(32, 8), 0, stream>>>(W1, Bt1, F_IN, D1);
    split_wt<<<dim3(D2 / 32, D1 / 32),   dim3(32, 8), 0, stream>>>(W2, Bt2, D1, D2);
    split_wt<<<dim3(D3 / 32, D2 / 32),   dim3(32, 8), 0, stream>>>(W3, Bt3, D2, D3);
    split_wt<<<dim3(HIDG / 32, D3 / 32), dim3(32, 8), 0, stream>>>(Wg1, Btg, D3, HIDG);

    // ---- layer-1 input split ----
    split_x<<<dim3((N_NODES * F_IN / 4 + 255) / 256), dim3(256), 0, stream>>>(node_feat, Xsp, N_NODES, F_IN);

    // ---- layer 1 (fp32 feat path) ----
    gemm_mfma<false, false, false><<<dim3(157 * 2), dim3(256), 0, stream>>>(Xsp, Bt1, nullptr, bufA, N_NODES, D1, F_IN, 2);
    attn_lr<<<dim3(N_NODES), dim3(256), 0, stream>>>(bufA, al1, ar1, el, er, O1);
    attn_softmax<<<dim3(N_NODES), dim3(64), 0, stream>>>(el, er, rowptr, csr_src, csr_e, rden);
    aggregate<1, 6><<<dim3(N_NODES), dim3(256), 0, stream>>>(bufA, csr_e, rden, rowptr, csr_src, b1, Xsp, D1);

    // ---- layer 2 (bf16 feat plane) ----
    gemm_mfma<false, false, true><<<dim3(157 * 4), dim3(256), 0, stream>>>(Xsp, Bt2, nullptr, featb, N_NODES, D2, D1, 4);
    attn_lr_b<<<dim3(N_NODES), dim3(256), 0, stream>>>(featb, al2, ar2, el, er, O2);
    attn_softmax<<<dim3(N_NODES), dim3(64), 0, stream>>>(el, er, rowptr, csr_src, csr_e, rden);
    aggregate_b<2, 7><<<dim3(N_NODES), dim3(256), 0, stream>>>(featb, csr_e, rden, rowptr, csr_src, b2, Xsp, D2);

    // ---- layer 3 (bf16 feat plane) ----
    gemm_mfma<false, false, true><<<dim3(157 * 8), dim3(256), 0, stream>>>(Xsp, Bt3, nullptr, featb, N_NODES, D3, D2, 8);
    attn_lr_b<<<dim3(N_NODES), dim3(256), 0, stream>>>(featb, al3, ar3, el, er, O3);
    attn_softmax<<<dim3(N_NODES), dim3(64), 0, stream>>>(el, er, rowptr, csr_src, csr_e, rden);
    aggregate_b<4, 8><<<dim3(N_NODES), dim3(256), 0, stream>>>(featb, csr_e, rden, rowptr, csr_src, b3, Xsp, D3);

    // ---- pooling ----
    gemm_mfma<true, true, false><<<dim3(157), dim3(256), 0, stream>>>(Xsp, Btg, bg1, gh, N_NODES, HIDG, D3, 1);
    gate_kernel<<<dim3(N_NODES), dim3(128), 0, stream>>>(gh, Wg2, bg2, gate);
    gate_stats<<<dim3(N_GRAPH), dim3(64), 0, stream>>>(gate, gptr, anorm);
    pool_gather<<<dim3(D3 / 256, N_GRAPH), dim3(256), 0, stream>>>(Xsp, anorm, gptr, gemb);
    heads_kernel<<<dim3(N_GRAPH), dim3(128), 0, stream>>>(gemb, Wmu, bmu, Wlv, blv, out);
}

// Round 5
// 568.748 us; speedup vs baseline: 5.0775x; 1.1503x over previous
//
#include <hip/hip_runtime.h>
#include <math.h>

// ---- problem constants (fixed by the reference) ----
constexpr int N_NODES = 20000;
constexpr int N_EDGES = 320000;
constexpr int N_GRAPH = 200;
constexpr int F_IN    = 128;
constexpr int NH      = 4;
constexpr int O1 = 64,  O2 = 128, O3 = 256;
constexpr int D1 = 256, D2 = 512, D3 = 1024;
constexpr int LAT  = 128;
constexpr int HIDG = 128;
constexpr float NEG_SLOPE = 0.2f;

typedef __attribute__((ext_vector_type(8))) short bf16x8;
typedef __attribute__((ext_vector_type(4))) float f32x4;
typedef __attribute__((ext_vector_type(2))) ushort ushortx2;
typedef __attribute__((ext_vector_type(4))) ushort ushortx4;
typedef __attribute__((ext_vector_type(8))) ushort ushortx8;

template<int R> struct VecU;
template<> struct VecU<2> { using T = ushortx2; };
template<> struct VecU<4> { using T = ushortx4; };
template<> struct VecU<8> { using T = ushortx8; };

// bf16 split: x ~= hi + lo, both RNE-rounded bf16 (stored as raw ushort)
__device__ inline void bsplit(float x, ushort& h, ushort& l) {
    unsigned u = __float_as_uint(x);
    unsigned rh = (u + 0x7fffu + ((u >> 16) & 1u)) & 0xffff0000u;
    h = (ushort)(rh >> 16);
    float res = x - __uint_as_float(rh);
    unsigned u2 = __float_as_uint(res);
    l = (ushort)((u2 + 0x7fffu + ((u2 >> 16) & 1u)) >> 16);
}
__device__ inline ushort f2bf(float x) {
    unsigned u = __float_as_uint(x);
    return (ushort)((u + 0x7fffu + ((u >> 16) & 1u)) >> 16);
}
__device__ inline float bf2f(ushort u) { return __uint_as_float(((unsigned)u) << 16); }

// ================= CSR build =================
__global__ void zero_int(int* __restrict__ p, int n) {
    int i = blockIdx.x * blockDim.x + threadIdx.x;
    if (i < n) p[i] = 0;
}

__global__ void count_deg(const int* __restrict__ dst, int* __restrict__ deg) {
    int e = blockIdx.x * blockDim.x + threadIdx.x;
    if (e < N_EDGES) atomicAdd(&deg[dst[e]], 1);
}

constexpr int SCAN_B = 512;
__global__ __launch_bounds__(SCAN_B)
void scan1(const int* __restrict__ deg, int* __restrict__ rowptr, int* __restrict__ bsum) {
    __shared__ int s[SCAN_B];
    int tid = threadIdx.x;
    int i = blockIdx.x * SCAN_B + tid;
    int v = (i < N_NODES) ? deg[i] : 0;
    s[tid] = v;
    __syncthreads();
    for (int off = 1; off < SCAN_B; off <<= 1) {
        int add = (tid >= off) ? s[tid - off] : 0;
        __syncthreads();
        s[tid] += add;
        __syncthreads();
    }
    if (i < N_NODES) rowptr[i] = s[tid] - v;
    if (tid == SCAN_B - 1) bsum[blockIdx.x] = s[tid];
}

__global__ void scan2(const int* __restrict__ bsum, int* __restrict__ boff, int nblk) {
    if (threadIdx.x == 0 && blockIdx.x == 0) {
        int run = 0;
        for (int b = 0; b < nblk; ++b) { boff[b] = run; run += bsum[b]; }
    }
}

__global__ __launch_bounds__(SCAN_B)
void scan3(int* __restrict__ rowptr, const int* __restrict__ boff, int* __restrict__ pos) {
    int i = blockIdx.x * SCAN_B + threadIdx.x;
    if (i < N_NODES) {
        int v = rowptr[i] + boff[blockIdx.x];
        rowptr[i] = v;
        pos[i] = v;
    }
    if (i == 0) rowptr[N_NODES] = N_EDGES;
}

__global__ void fill_csr(const int* __restrict__ src, const int* __restrict__ dst,
                         int* __restrict__ pos, int* __restrict__ csr_src) {
    int e = blockIdx.x * blockDim.x + threadIdx.x;
    if (e >= N_EDGES) return;
    int slot = atomicAdd(&pos[dst[e]], 1);
    csr_src[slot] = src[e];
}

__global__ void gptr_kernel(const int* __restrict__ gid, int* __restrict__ gptr) {
    int g = blockIdx.x * blockDim.x + threadIdx.x;
    if (g > N_GRAPH) return;
    int lo = 0, hi = N_NODES;
    while (lo < hi) { int mid = (lo + hi) >> 1; if (gid[mid] < g) lo = mid + 1; else hi = mid; }
    gptr[g] = lo;
}

// ================= conversion kernels =================
__global__ void split_x(const float* __restrict__ X, ushort* __restrict__ S, int M, int K) {
    int i = blockIdx.x * 256 + threadIdx.x;
    int total = (M * K) >> 2;
    if (i >= total) return;
    int e0 = i << 2;
    int m = e0 / K, k = e0 % K;
    float4 v = *(const float4*)&X[(size_t)m * K + k];
    ushort h[4], l[4];
    bsplit(v.x, h[0], l[0]); bsplit(v.y, h[1], l[1]);
    bsplit(v.z, h[2], l[2]); bsplit(v.w, h[3], l[3]);
    uint2 hp, lp;
    hp.x = (unsigned)h[0] | ((unsigned)h[1] << 16);
    hp.y = (unsigned)h[2] | ((unsigned)h[3] << 16);
    lp.x = (unsigned)l[0] | ((unsigned)l[1] << 16);
    lp.y = (unsigned)l[2] | ((unsigned)l[3] << 16);
    *(uint2*)&S[(size_t)m * 2 * K + k] = hp;
    *(uint2*)&S[(size_t)m * 2 * K + K + k] = lp;
}

__global__ __launch_bounds__(256)
void split_wt(const float* __restrict__ W, ushort* __restrict__ Bt, int K, int N) {
    __shared__ float t[32][33];
    int n0 = blockIdx.x * 32, k0 = blockIdx.y * 32;
    int tx = threadIdx.x, ty = threadIdx.y;   // 32 x 8
    for (int j = 0; j < 32; j += 8)
        t[ty + j][tx] = W[(size_t)(k0 + ty + j) * N + n0 + tx];
    __syncthreads();
    for (int j = 0; j < 32; j += 8) {
        float v = t[tx][ty + j];
        int n = n0 + ty + j, k = k0 + tx;
        ushort h, l;
        bsplit(v, h, l);
        Bt[(size_t)n * 2 * K + k] = h;
        Bt[(size_t)n * 2 * K + K + k] = l;
    }
}

// ================= bf16x3 merged-segment MFMA GEMM =================
// C = A@B, fp32-class accuracy: AhBh + AlBh + AhBl in ONE K-pass.
// Asp: [M][2K] (hi|lo). Bt: [N][2K] (hi|lo of B^T). 128x128 tile, BK=64.
// LDS: 4 planes (Ah, Al, Bh, Bl) of 128x64 ushort = 64 KB.
// OMODE: 0 = f32 out, 1 = bf16 out, 2 = f32 K-split partial (blockIdx.y chunk)
#define GLOAD_LDS16(g, s) \
    __builtin_amdgcn_global_load_lds((const __attribute__((address_space(1))) void*)(g), \
                                     (__attribute__((address_space(3))) void*)(s), 16, 0, 0)

template<bool BIAS, bool RELU, int OMODE>
__global__ __launch_bounds__(256)
void gemm_mfma(const ushort* __restrict__ Asp, const ushort* __restrict__ Bt,
               const float* __restrict__ bias, void* __restrict__ Cout,
               int M, int N, int K, int ntn, int kchunk) {
    __shared__ __align__(16) ushort lds[4 * 128 * 64];   // 64 KB
    constexpr int AH = 0, AL = 128 * 64, BH = 2 * 128 * 64, BL = 3 * 128 * 64;

    const int nwg = gridDim.x;
    int bid = blockIdx.x;
    int q = nwg >> 3, r = nwg & 7;
    int xcd = bid & 7, local = bid >> 3;
    int wg = (xcd < r) ? (xcd * (q + 1) + local) : (r * (q + 1) + (xcd - r) * q + local);
    const int tm = wg / ntn, tn = wg % ntn;

    const int tid = threadIdx.x;
    const int w = tid >> 6, l = tid & 63;
    const int wr = w >> 1, wc = w & 1;
    const size_t sA = 2 * (size_t)K;

    const int ld8 = l >> 3;
    const int stg_col = ((l & 7) ^ ld8) << 3;
    const int r15 = l & 15, kq = l >> 4;
    const int swz = (l & 7) << 4;

    const int k_begin = blockIdx.y * kchunk;
    const int k_end = (k_begin + kchunk < K) ? (k_begin + kchunk) : K;

    f32x4 acc[4][4];
    #pragma unroll
    for (int m = 0; m < 4; ++m)
        #pragma unroll
        for (int n = 0; n < 4; ++n)
            acc[m][n] = 0.f;

    for (int k0 = k_begin; k0 < k_end; k0 += 64) {
        #pragma unroll
        for (int i = 0; i < 4; ++i) {
            int r0 = w * 32 + i * 8;
            int garow = tm * 128 + r0 + ld8;
            if (garow > M - 1) garow = M - 1;
            const ushort* gaH = Asp + (size_t)garow * sA + k0 + stg_col;
            GLOAD_LDS16(gaH, &lds[AH + r0 * 64]);
            GLOAD_LDS16(gaH + K, &lds[AL + r0 * 64]);
            int gbrow = tn * 128 + r0 + ld8;
            const ushort* gbH = Bt + (size_t)gbrow * sA + k0 + stg_col;
            GLOAD_LDS16(gbH, &lds[BH + r0 * 64]);
            GLOAD_LDS16(gbH + K, &lds[BL + r0 * 64]);
        }
        asm volatile("s_waitcnt vmcnt(0)");
        __syncthreads();

        #pragma unroll
        for (int ks = 0; ks < 2; ++ks) {
            const int kbyte = (ks * 64 + kq * 16) ^ swz;
            bf16x8 ah[4], bh[4], xl[4];
            #pragma unroll
            for (int m = 0; m < 4; ++m) {
                int row = wr * 64 + m * 16 + r15;
                ah[m] = *(const bf16x8*)((const char*)&lds[AH] + row * 128 + kbyte);
            }
            #pragma unroll
            for (int n = 0; n < 4; ++n) {
                int row = wc * 64 + n * 16 + r15;
                bh[n] = *(const bf16x8*)((const char*)&lds[BH] + row * 128 + kbyte);
            }
            #pragma unroll
            for (int m = 0; m < 4; ++m)
                #pragma unroll
                for (int n = 0; n < 4; ++n)
                    acc[m][n] = __builtin_amdgcn_mfma_f32_16x16x32_bf16(ah[m], bh[n], acc[m][n], 0, 0, 0);
            #pragma unroll
            for (int m = 0; m < 4; ++m) {
                int row = wr * 64 + m * 16 + r15;
                xl[m] = *(const bf16x8*)((const char*)&lds[AL] + row * 128 + kbyte);
            }
            #pragma unroll
            for (int m = 0; m < 4; ++m)
                #pragma unroll
                for (int n = 0; n < 4; ++n)
                    acc[m][n] = __builtin_amdgcn_mfma_f32_16x16x32_bf16(xl[m], bh[n], acc[m][n], 0, 0, 0);
            #pragma unroll
            for (int n = 0; n < 4; ++n) {
                int row = wc * 64 + n * 16 + r15;
                xl[n] = *(const bf16x8*)((const char*)&lds[BL] + row * 128 + kbyte);
            }
            #pragma unroll
            for (int m = 0; m < 4; ++m)
                #pragma unroll
                for (int n = 0; n < 4; ++n)
                    acc[m][n] = __builtin_amdgcn_mfma_f32_16x16x32_bf16(ah[m], xl[n], acc[m][n], 0, 0, 0);
        }
        __syncthreads();
    }

    // ---- epilogue ----
    #pragma unroll
    for (int m = 0; m < 4; ++m) {
        #pragma unroll
        for (int n = 0; n < 4; ++n) {
            #pragma unroll
            for (int j = 0; j < 4; ++j) {
                int row = tm * 128 + wr * 64 + m * 16 + kq * 4 + j;
                int col = tn * 128 + wc * 64 + n * 16 + r15;
                if (row < M) {
                    float v = acc[m][n][j];
                    if (BIAS) v += bias[col];
                    if (RELU) v = fmaxf(v, 0.f);
                    if (OMODE == 1)
                        ((ushort*)Cout)[(size_t)row * N + col] = f2bf(v);
                    else if (OMODE == 2)
                        ((float*)Cout)[(size_t)blockIdx.y * M * N + (size_t)row * N + col] = v;
                    else
                        ((float*)Cout)[(size_t)row * N + col] = v;
                }
            }
        }
    }
}

// ================= per-node attention halves (bf16 plane) =================
__global__ __launch_bounds__(256)
void attn_lr_b(const ushort* __restrict__ feat, const float* __restrict__ al,
               const float* __restrict__ ar, float* __restrict__ el,
               float* __restrict__ er, int O) {
    int n = blockIdx.x;
    int h = threadIdx.x >> 6;
    int lane = threadIdx.x & 63;
    const ushort* fr = feat + (size_t)n * (NH * O) + h * O;
    float sl = 0.f, sr = 0.f;
    for (int o = lane; o < O; o += 64) {
        float f = bf2f(fr[o]);
        sl += f * al[h * O + o];
        sr += f * ar[h * O + o];
    }
    #pragma unroll
    for (int off = 32; off; off >>= 1) {
        sl += __shfl_down(sl, off);
        sr += __shfl_down(sr, off);
    }
    if (lane == 0) {
        el[n * NH + h] = sl;
        er[n * NH + h] = sr;
    }
}

// ================= per-dst edge softmax over CSR =================
__global__ __launch_bounds__(64)
void attn_softmax(const float* __restrict__ el, const float* __restrict__ er,
                  const int* __restrict__ rowptr, const int* __restrict__ csr_src,
                  float* __restrict__ csr_e, float* __restrict__ rden) {
    int d = blockIdx.x;
    int lane = threadIdx.x;
    int base = rowptr[d], end = rowptr[d + 1];
    float erd[NH];
    #pragma unroll
    for (int h = 0; h < NH; ++h) erd[h] = er[d * NH + h];

    float mx[NH] = {-INFINITY, -INFINITY, -INFINITY, -INFINITY};
    for (int s = base + lane; s < end; s += 64) {
        int sn = csr_src[s];
        #pragma unroll
        for (int h = 0; h < NH; ++h) {
            float v = el[sn * NH + h] + erd[h];
            v = (v >= 0.f) ? v : NEG_SLOPE * v;
            csr_e[s * NH + h] = v;
            mx[h] = fmaxf(mx[h], v);
        }
    }
    #pragma unroll
    for (int h = 0; h < NH; ++h)
        #pragma unroll
        for (int off = 32; off; off >>= 1)
            mx[h] = fmaxf(mx[h], __shfl_xor(mx[h], off));

    float sm[NH] = {0.f, 0.f, 0.f, 0.f};
    for (int s = base + lane; s < end; s += 64) {
        #pragma unroll
        for (int h = 0; h < NH; ++h) {
            float ex = expf(csr_e[s * NH + h] - mx[h]);
            csr_e[s * NH + h] = ex;
            sm[h] += ex;
        }
    }
    #pragma unroll
    for (int h = 0; h < NH; ++h)
        #pragma unroll
        for (int off = 32; off; off >>= 1)
            sm[h] += __shfl_xor(sm[h], off);

    if (lane == 0) {
        #pragma unroll
        for (int h = 0; h < NH; ++h)
            rden[d * NH + h] = 1.f / fmaxf(sm[h], 1e-9f);
    }
}

// ================= gather aggregation (bf16 feat plane) =====================
// 128 threads; thread t owns cols [t*REGS, (t+1)*REGS); D = 128*REGS.
template<int REGS, int OSHIFT>
__global__ __launch_bounds__(128)
void aggregate_b(const ushort* __restrict__ feat, const float* __restrict__ csr_e,
                 const float* __restrict__ rden, const int* __restrict__ rowptr,
                 const int* __restrict__ csr_src, const float* __restrict__ bias,
                 ushort* __restrict__ Ssp, int D) {
    using VT = typename VecU<REGS>::T;
    int d = blockIdx.x;
    int t = threadIdx.x;
    int base = rowptr[d], end = rowptr[d + 1];
    const int col0 = t * REGS;
    const int h = col0 >> OSHIFT;

    float acc[REGS];
    #pragma unroll
    for (int k = 0; k < REGS; ++k) acc[k] = 0.f;

    int s = base;
    for (; s + 1 < end; s += 2) {
        int sn0 = csr_src[s], sn1 = csr_src[s + 1];
        float a0 = csr_e[s * NH + h], a1 = csr_e[(s + 1) * NH + h];
        VT u0 = *(const VT*)(feat + (size_t)sn0 * D + col0);
        VT u1 = *(const VT*)(feat + (size_t)sn1 * D + col0);
        #pragma unroll
        for (int k = 0; k < REGS; ++k) acc[k] += bf2f(u0[k]) * a0;
        #pragma unroll
        for (int k = 0; k < REGS; ++k) acc[k] += bf2f(u1[k]) * a1;
    }
    if (s < end) {
        int sn = csr_src[s];
        float a = csr_e[s * NH + h];
        VT u = *(const VT*)(feat + (size_t)sn * D + col0);
        #pragma unroll
        for (int k = 0; k < REGS; ++k) acc[k] += bf2f(u[k]) * a;
    }

    float rd = rden[d * NH + h];
    ushort hh[REGS], ll[REGS];
    #pragma unroll
    for (int k = 0; k < REGS; ++k) {
        float v = acc[k] * rd + bias[col0 + k];
        v = (v > 0.f) ? v : expm1f(v);
        bsplit(v, hh[k], ll[k]);
    }
    ushort* hrow = Ssp + (size_t)d * 2 * D;
    #pragma unroll
    for (int k = 0; k < REGS; ++k) {
        hrow[col0 + k] = hh[k];
        hrow[D + col0 + k] = ll[k];
    }
}

// ================= gate reduce: partials -> gate scalar =================
// part[4][N][128]; gate[n] = relu(sum_kc part + bg1) . Wg2 + bg2
__global__ __launch_bounds__(128)
void gate_reduce(const float* __restrict__ part, const float* __restrict__ bg1,
                 const float* __restrict__ Wg2, const float* __restrict__ bg2,
                 float* __restrict__ gate) {
    int n = blockIdx.x;
    int t = threadIdx.x;
    constexpr size_t CH = (size_t)N_NODES * HIDG;
    size_t idx = (size_t)n * HIDG + t;
    float v = part[idx] + part[CH + idx] + part[2 * CH + idx] + part[3 * CH + idx] + bg1[t];
    v = fmaxf(v, 0.f) * Wg2[t];
    __shared__ float red[128];
    red[t] = v;
    __syncthreads();
    for (int s = 64; s; s >>= 1) {
        if (t < s) red[t] += red[t + s];
        __syncthreads();
    }
    if (t == 0) gate[n] = red[0] + bg2[0];
}

__global__ __launch_bounds__(64)
void gate_stats(const float* __restrict__ gate, const int* __restrict__ gptr,
                float* __restrict__ anorm) {
    int g = blockIdx.x;
    int lane = threadIdx.x;
    int s = gptr[g], e = gptr[g + 1];
    float m = -INFINITY;
    for (int n = s + lane; n < e; n += 64) m = fmaxf(m, gate[n]);
    #pragma unroll
    for (int off = 32; off; off >>= 1) m = fmaxf(m, __shfl_xor(m, off));
    float sum = 0.f;
    for (int n = s + lane; n < e; n += 64) sum += expf(gate[n] - m);
    #pragma unroll
    for (int off = 32; off; off >>= 1) sum += __shfl_xor(sum, off);
    float inv = 1.f / fmaxf(sum, 1e-9f);
    for (int n = s + lane; n < e; n += 64) anorm[n] = expf(gate[n] - m) * inv;
}

// gemb[g] = sum_n anorm[n] * h3[n]  (h3 read from split bf16)
__global__ __launch_bounds__(256)
void pool_gather(const ushort* __restrict__ h3sp, const float* __restrict__ anorm,
                 const int* __restrict__ gptr, float* __restrict__ gemb) {
    int g = blockIdx.y;
    int col = blockIdx.x * 256 + threadIdx.x;
    float acc = 0.f;
    int s = gptr[g], e = gptr[g + 1];
    for (int n = s; n < e; ++n) {
        const ushort* row = h3sp + (size_t)n * 2 * D3;
        acc += anorm[n] * (bf2f(row[col]) + bf2f(row[D3 + col]));
    }
    gemb[(size_t)g * D3 + col] = acc;
}

// ================= heads =================
__global__ __launch_bounds__(128)
void heads_kernel(const float* __restrict__ gemb, const float* __restrict__ Wmu,
                  const float* __restrict__ bmu, const float* __restrict__ Wlv,
                  const float* __restrict__ blv, float* __restrict__ out) {
    int g = blockIdx.x;
    int j = threadIdx.x;
    __shared__ float e[D3];
    for (int k = threadIdx.x; k < D3; k += 128) e[k] = gemb[(size_t)g * D3 + k];
    __syncthreads();
    float smu = 0.f, slv = 0.f;
    for (int k = 0; k < D3; ++k) {
        float v = e[k];
        smu += v * Wmu[k * LAT + j];
        slv += v * Wlv[k * LAT + j];
    }
    out[g * LAT + j] = smu + bmu[j];
    out[N_GRAPH * LAT + g * LAT + j] = slv + blv[j];
}

// ================= host launch =================
extern "C" void kernel_launch(void* const* d_in, const int* in_sizes, int n_in,
                              void* d_out, int out_size, void* d_ws, size_t ws_size,
                              hipStream_t stream) {
    const float* node_feat = (const float*)d_in[0];
    const int*   src = (const int*)d_in[1];
    const int*   dst = (const int*)d_in[2];
    const int*   gid = (const int*)d_in[3];
    const float* W1  = (const float*)d_in[4];
    const float* al1 = (const float*)d_in[5];
    const float* ar1 = (const float*)d_in[6];
    const float* b1  = (const float*)d_in[7];
    const float* W2  = (const float*)d_in[8];
    const float* al2 = (const float*)d_in[9];
    const float* ar2 = (const float*)d_in[10];
    const float* b2  = (const float*)d_in[11];
    const float* W3  = (const float*)d_in[12];
    const float* al3 = (const float*)d_in[13];
    const float* ar3 = (const float*)d_in[14];
    const float* b3  = (const float*)d_in[15];
    const float* Wg1 = (const float*)d_in[16];
    const float* bg1 = (const float*)d_in[17];
    const float* Wg2 = (const float*)d_in[18];
    const float* bg2 = (const float*)d_in[19];
    const float* Wmu = (const float*)d_in[20];
    const float* bmu = (const float*)d_in[21];
    const float* Wlv = (const float*)d_in[22];
    const float* blv = (const float*)d_in[23];
    float* out = (float*)d_out;

    // ---- workspace carve ----
    char* wsb = (char*)d_ws;
    float* bufA   = (float*)wsb;                                   // N*D3 f32 region
    wsb += (size_t)N_NODES * D3 * 4;
    ushort* Xsp   = (ushort*)wsb;                                  // N*2048 bf16 (split acts)
    wsb += (size_t)N_NODES * 2048 * 2;
    ushort* Bt1   = (ushort*)wsb; wsb += (size_t)D1 * 2 * F_IN * 2;
    ushort* Bt2   = (ushort*)wsb; wsb += (size_t)D2 * 2 * D1 * 2;
    ushort* Bt3   = (ushort*)wsb; wsb += (size_t)D3 * 2 * D2 * 2;
    ushort* Btg   = (ushort*)wsb; wsb += (size_t)HIDG * 2 * D3 * 2;
    float* el     = (float*)wsb;  wsb += (size_t)N_NODES * NH * 4;
    float* er     = (float*)wsb;  wsb += (size_t)N_NODES * NH * 4;
    float* rden   = (float*)wsb;  wsb += (size_t)N_NODES * NH * 4;
    float* csr_e  = (float*)wsb;  wsb += (size_t)N_EDGES * NH * 4;
    float* gate   = (float*)wsb;  wsb += (size_t)N_NODES * 4;
    float* anorm  = (float*)wsb;  wsb += (size_t)N_NODES * 4;
    int* deg      = (int*)wsb;    wsb += (size_t)N_NODES * 4;
    int* rowptr   = (int*)wsb;    wsb += (size_t)(N_NODES + 1) * 4;
    int* pos      = (int*)wsb;    wsb += (size_t)N_NODES * 4;
    int* csr_src  = (int*)wsb;    wsb += (size_t)N_EDGES * 4;
    int* bsum     = (int*)wsb;    wsb += 64 * 4;
    int* boff     = (int*)wsb;    wsb += 64 * 4;
    int* gptr     = (int*)wsb;    wsb += (size_t)(N_GRAPH + 1) * 4;
    ushort* featb = (ushort*)bufA;                                 // bf16 feat plane alias
    float* partial = bufA;                                         // pool K-split partials (4*N*128)
    float* gemb   = bufA + (size_t)4 * N_NODES * HIDG;             // G*D3

    // ---- CSR build ----
    constexpr int NBLK = (N_NODES + SCAN_B - 1) / SCAN_B;
    zero_int<<<dim3((N_NODES + 255) / 256), dim3(256), 0, stream>>>(deg, N_NODES);
    count_deg<<<dim3((N_EDGES + 255) / 256), dim3(256), 0, stream>>>(dst, deg);
    scan1<<<dim3(NBLK), dim3(SCAN_B), 0, stream>>>(deg, rowptr, bsum);
    scan2<<<dim3(1), dim3(64), 0, stream>>>(bsum, boff, NBLK);
    scan3<<<dim3(NBLK), dim3(SCAN_B), 0, stream>>>(rowptr, boff, pos);
    fill_csr<<<dim3((N_EDGES + 255) / 256), dim3(256), 0, stream>>>(src, dst, pos, csr_src);
    gptr_kernel<<<dim3(1), dim3(256), 0, stream>>>(gid, gptr);

    // ---- weight splits (transposed) ----
    split_wt<<<dim3(D1 / 32, F_IN / 32), dim3(32, 8), 0, stream>>>(W1, Bt1, F_IN, D1);
    split_wt<<<dim3(D2 / 32, D1 / 32),   dim3(32, 8), 0, stream>>>(W2, Bt2, D1, D2);
    split_wt<<<dim3(D3 / 32, D2 / 32),   dim3(32, 8), 0, stream>>>(W3, Bt3, D2, D3);
    split_wt<<<dim3(HIDG / 32, D3 / 32), dim3(32, 8), 0, stream>>>(Wg1, Btg, D3, HIDG);

    // ---- layer-1 input split ----
    split_x<<<dim3((N_NODES * F_IN / 4 + 255) / 256), dim3(256), 0, stream>>>(node_feat, Xsp, N_NODES, F_IN);

    // ---- layer 1 ----
    gemm_mfma<false, false, 1><<<dim3(157 * 2), dim3(256), 0, stream>>>(Xsp, Bt1, nullptr, featb, N_NODES, D1, F_IN, 2, F_IN);
    attn_lr_b<<<dim3(N_NODES), dim3(256), 0, stream>>>(featb, al1, ar1, el, er, O1);
    attn_softmax<<<dim3(N_NODES), dim3(64), 0, stream>>>(el, er, rowptr, csr_src, csr_e, rden);
    aggregate_b<2, 6><<<dim3(N_NODES), dim3(128), 0, stream>>>(featb, csr_e, rden, rowptr, csr_src, b1, Xsp, D1);

    // ---- layer 2 ----
    gemm_mfma<false, false, 1><<<dim3(157 * 4), dim3(256), 0, stream>>>(Xsp, Bt2, nullptr, featb, N_NODES, D2, D1, 4, D1);
    attn_lr_b<<<dim3(N_NODES), dim3(256), 0, stream>>>(featb, al2, ar2, el, er, O2);
    attn_softmax<<<dim3(N_NODES), dim3(64), 0, stream>>>(el, er, rowptr, csr_src, csr_e, rden);
    aggregate_b<4, 7><<<dim3(N_NODES), dim3(128), 0, stream>>>(featb, csr_e, rden, rowptr, csr_src, b2, Xsp, D2);

    // ---- layer 3 ----
    gemm_mfma<false, false, 1><<<dim3(157 * 8), dim3(256), 0, stream>>>(Xsp, Bt3, nullptr, featb, N_NODES, D3, D2, 8, D2);
    attn_lr_b<<<dim3(N_NODES), dim3(256), 0, stream>>>(featb, al3, ar3, el, er, O3);
    attn_softmax<<<dim3(N_NODES), dim3(64), 0, stream>>>(el, er, rowptr, csr_src, csr_e, rden);
    aggregate_b<8, 8><<<dim3(N_NODES), dim3(128), 0, stream>>>(featb, csr_e, rden, rowptr, csr_src, b3, Xsp, D3);

    // ---- pooling: K-split x4 gate GEMM -> fused reduce ----
    gemm_mfma<false, false, 2><<<dim3(157, 4), dim3(256), 0, stream>>>(Xsp, Btg, nullptr, partial, N_NODES, HIDG, D3, 1, D3 / 4);
    gate_reduce<<<dim3(N_NODES), dim3(128), 0, stream>>>(partial, bg1, Wg2, bg2, gate);
    gate_stats<<<dim3(N_GRAPH), dim3(64), 0, stream>>>(gate, gptr, anorm);
    pool_gather<<<dim3(D3 / 256, N_GRAPH), dim3(256), 0, stream>>>(Xsp, anorm, gptr, gemb);
    heads_kernel<<<dim3(N_GRAPH), dim3(128), 0, stream>>>(gemb, Wmu, bmu, Wlv, blv, out);
}

// Round 6
// 529.091 us; speedup vs baseline: 5.4581x; 1.0750x over previous
//
#include <hip/hip_runtime.h>
#include <math.h>

// ---- problem constants (fixed by the reference) ----
constexpr int N_NODES = 20000;
constexpr int N_EDGES = 320000;
constexpr int N_GRAPH = 200;
constexpr int F_IN    = 128;
constexpr int NH      = 4;
constexpr int O1 = 64,  O2 = 128, O3 = 256;
constexpr int D1 = 256, D2 = 512, D3 = 1024;
constexpr int LAT  = 128;
constexpr int HIDG = 128;
constexpr float NEG_SLOPE = 0.2f;

typedef __attribute__((ext_vector_type(8))) short bf16x8;
typedef __attribute__((ext_vector_type(4))) float f32x4;
typedef __attribute__((ext_vector_type(2))) ushort ushortx2;
typedef __attribute__((ext_vector_type(4))) ushort ushortx4;
typedef __attribute__((ext_vector_type(8))) ushort ushortx8;

template<int R> struct VecU;
template<> struct VecU<2> { using T = ushortx2; };
template<> struct VecU<4> { using T = ushortx4; };
template<> struct VecU<8> { using T = ushortx8; };

// bf16 split: x ~= hi + lo, both RNE-rounded bf16 (stored as raw ushort)
__device__ inline void bsplit(float x, ushort& h, ushort& l) {
    unsigned u = __float_as_uint(x);
    unsigned rh = (u + 0x7fffu + ((u >> 16) & 1u)) & 0xffff0000u;
    h = (ushort)(rh >> 16);
    float res = x - __uint_as_float(rh);
    unsigned u2 = __float_as_uint(res);
    l = (ushort)((u2 + 0x7fffu + ((u2 >> 16) & 1u)) >> 16);
}
__device__ inline ushort f2bf(float x) {
    unsigned u = __float_as_uint(x);
    return (ushort)((u + 0x7fffu + ((u >> 16) & 1u)) >> 16);
}
__device__ inline float bf2f(ushort u) { return __uint_as_float(((unsigned)u) << 16); }

// ================= CSR build =================
__global__ void zero_int(int* __restrict__ p, int n) {
    int i = blockIdx.x * blockDim.x + threadIdx.x;
    if (i < n) p[i] = 0;
}

__global__ void count_deg(const int* __restrict__ dst, int* __restrict__ deg) {
    int e = blockIdx.x * blockDim.x + threadIdx.x;
    if (e < N_EDGES) atomicAdd(&deg[dst[e]], 1);
}

constexpr int SCAN_B = 512;
__global__ __launch_bounds__(SCAN_B)
void scan1(const int* __restrict__ deg, int* __restrict__ rowptr, int* __restrict__ bsum) {
    __shared__ int s[SCAN_B];
    int tid = threadIdx.x;
    int i = blockIdx.x * SCAN_B + tid;
    int v = (i < N_NODES) ? deg[i] : 0;
    s[tid] = v;
    __syncthreads();
    for (int off = 1; off < SCAN_B; off <<= 1) {
        int add = (tid >= off) ? s[tid - off] : 0;
        __syncthreads();
        s[tid] += add;
        __syncthreads();
    }
    if (i < N_NODES) rowptr[i] = s[tid] - v;
    if (tid == SCAN_B - 1) bsum[blockIdx.x] = s[tid];
}

__global__ void scan2(const int* __restrict__ bsum, int* __restrict__ boff, int nblk) {
    if (threadIdx.x == 0 && blockIdx.x == 0) {
        int run = 0;
        for (int b = 0; b < nblk; ++b) { boff[b] = run; run += bsum[b]; }
    }
}

__global__ __launch_bounds__(SCAN_B)
void scan3(int* __restrict__ rowptr, const int* __restrict__ boff, int* __restrict__ pos) {
    int i = blockIdx.x * SCAN_B + threadIdx.x;
    if (i < N_NODES) {
        int v = rowptr[i] + boff[blockIdx.x];
        rowptr[i] = v;
        pos[i] = v;
    }
    if (i == 0) rowptr[N_NODES] = N_EDGES;
}

__global__ void fill_csr(const int* __restrict__ src, const int* __restrict__ dst,
                         int* __restrict__ pos, int* __restrict__ csr_src) {
    int e = blockIdx.x * blockDim.x + threadIdx.x;
    if (e >= N_EDGES) return;
    int slot = atomicAdd(&pos[dst[e]], 1);
    csr_src[slot] = src[e];
}

__global__ void gptr_kernel(const int* __restrict__ gid, int* __restrict__ gptr) {
    int g = blockIdx.x * blockDim.x + threadIdx.x;
    if (g > N_GRAPH) return;
    int lo = 0, hi = N_NODES;
    while (lo < hi) { int mid = (lo + hi) >> 1; if (gid[mid] < g) lo = mid + 1; else hi = mid; }
    gptr[g] = lo;
}

// ================= conversion kernels =================
__global__ void split_x(const float* __restrict__ X, ushort* __restrict__ S, int M, int K) {
    int i = blockIdx.x * 256 + threadIdx.x;
    int total = (M * K) >> 2;
    if (i >= total) return;
    int e0 = i << 2;
    int m = e0 / K, k = e0 % K;
    float4 v = *(const float4*)&X[(size_t)m * K + k];
    ushort h[4], l[4];
    bsplit(v.x, h[0], l[0]); bsplit(v.y, h[1], l[1]);
    bsplit(v.z, h[2], l[2]); bsplit(v.w, h[3], l[3]);
    uint2 hp, lp;
    hp.x = (unsigned)h[0] | ((unsigned)h[1] << 16);
    hp.y = (unsigned)h[2] | ((unsigned)h[3] << 16);
    lp.x = (unsigned)l[0] | ((unsigned)l[1] << 16);
    lp.y = (unsigned)l[2] | ((unsigned)l[3] << 16);
    *(uint2*)&S[(size_t)m * 2 * K + k] = hp;
    *(uint2*)&S[(size_t)m * 2 * K + K + k] = lp;
}

__global__ __launch_bounds__(256)
void split_wt(const float* __restrict__ W, ushort* __restrict__ Bt, int K, int N) {
    __shared__ float t[32][33];
    int n0 = blockIdx.x * 32, k0 = blockIdx.y * 32;
    int tx = threadIdx.x, ty = threadIdx.y;   // 32 x 8
    for (int j = 0; j < 32; j += 8)
        t[ty + j][tx] = W[(size_t)(k0 + ty + j) * N + n0 + tx];
    __syncthreads();
    for (int j = 0; j < 32; j += 8) {
        float v = t[tx][ty + j];
        int n = n0 + ty + j, k = k0 + tx;
        ushort h, l;
        bsplit(v, h, l);
        Bt[(size_t)n * 2 * K + k] = h;
        Bt[(size_t)n * 2 * K + K + k] = l;
    }
}

// ================= bf16x3 merged-segment MFMA GEMM =================
// C = A@B, fp32-class accuracy: AhBh + AlBh + AhBl in ONE K-pass.
// OMODE: 0 = f32 out, 1 = bf16 out, 2 = f32 K-split partial (blockIdx.y chunk)
#define GLOAD_LDS16(g, s) \
    __builtin_amdgcn_global_load_lds((const __attribute__((address_space(1))) void*)(g), \
                                     (__attribute__((address_space(3))) void*)(s), 16, 0, 0)

template<bool BIAS, bool RELU, int OMODE>
__global__ __launch_bounds__(256)
void gemm_mfma(const ushort* __restrict__ Asp, const ushort* __restrict__ Bt,
               const float* __restrict__ bias, void* __restrict__ Cout,
               int M, int N, int K, int ntn, int kchunk) {
    __shared__ __align__(16) ushort lds[4 * 128 * 64];   // 64 KB
    constexpr int AH = 0, AL = 128 * 64, BH = 2 * 128 * 64, BL = 3 * 128 * 64;

    const int nwg = gridDim.x;
    int bid = blockIdx.x;
    int q = nwg >> 3, r = nwg & 7;
    int xcd = bid & 7, local = bid >> 3;
    int wg = (xcd < r) ? (xcd * (q + 1) + local) : (r * (q + 1) + (xcd - r) * q + local);
    const int tm = wg / ntn, tn = wg % ntn;

    const int tid = threadIdx.x;
    const int w = tid >> 6, l = tid & 63;
    const int wr = w >> 1, wc = w & 1;
    const size_t sA = 2 * (size_t)K;

    const int ld8 = l >> 3;
    const int stg_col = ((l & 7) ^ ld8) << 3;
    const int r15 = l & 15, kq = l >> 4;
    const int swz = (l & 7) << 4;

    const int k_begin = blockIdx.y * kchunk;
    const int k_end = (k_begin + kchunk < K) ? (k_begin + kchunk) : K;

    f32x4 acc[4][4];
    #pragma unroll
    for (int m = 0; m < 4; ++m)
        #pragma unroll
        for (int n = 0; n < 4; ++n)
            acc[m][n] = 0.f;

    for (int k0 = k_begin; k0 < k_end; k0 += 64) {
        #pragma unroll
        for (int i = 0; i < 4; ++i) {
            int r0 = w * 32 + i * 8;
            int garow = tm * 128 + r0 + ld8;
            if (garow > M - 1) garow = M - 1;
            const ushort* gaH = Asp + (size_t)garow * sA + k0 + stg_col;
            GLOAD_LDS16(gaH, &lds[AH + r0 * 64]);
            GLOAD_LDS16(gaH + K, &lds[AL + r0 * 64]);
            int gbrow = tn * 128 + r0 + ld8;
            const ushort* gbH = Bt + (size_t)gbrow * sA + k0 + stg_col;
            GLOAD_LDS16(gbH, &lds[BH + r0 * 64]);
            GLOAD_LDS16(gbH + K, &lds[BL + r0 * 64]);
        }
        asm volatile("s_waitcnt vmcnt(0)");
        __syncthreads();

        #pragma unroll
        for (int ks = 0; ks < 2; ++ks) {
            const int kbyte = (ks * 64 + kq * 16) ^ swz;
            bf16x8 ah[4], bh[4], xl[4];
            #pragma unroll
            for (int m = 0; m < 4; ++m) {
                int row = wr * 64 + m * 16 + r15;
                ah[m] = *(const bf16x8*)((const char*)&lds[AH] + row * 128 + kbyte);
            }
            #pragma unroll
            for (int n = 0; n < 4; ++n) {
                int row = wc * 64 + n * 16 + r15;
                bh[n] = *(const bf16x8*)((const char*)&lds[BH] + row * 128 + kbyte);
            }
            #pragma unroll
            for (int m = 0; m < 4; ++m)
                #pragma unroll
                for (int n = 0; n < 4; ++n)
                    acc[m][n] = __builtin_amdgcn_mfma_f32_16x16x32_bf16(ah[m], bh[n], acc[m][n], 0, 0, 0);
            #pragma unroll
            for (int m = 0; m < 4; ++m) {
                int row = wr * 64 + m * 16 + r15;
                xl[m] = *(const bf16x8*)((const char*)&lds[AL] + row * 128 + kbyte);
            }
            #pragma unroll
            for (int m = 0; m < 4; ++m)
                #pragma unroll
                for (int n = 0; n < 4; ++n)
                    acc[m][n] = __builtin_amdgcn_mfma_f32_16x16x32_bf16(xl[m], bh[n], acc[m][n], 0, 0, 0);
            #pragma unroll
            for (int n = 0; n < 4; ++n) {
                int row = wc * 64 + n * 16 + r15;
                xl[n] = *(const bf16x8*)((const char*)&lds[BL] + row * 128 + kbyte);
            }
            #pragma unroll
            for (int m = 0; m < 4; ++m)
                #pragma unroll
                for (int n = 0; n < 4; ++n)
                    acc[m][n] = __builtin_amdgcn_mfma_f32_16x16x32_bf16(ah[m], xl[n], acc[m][n], 0, 0, 0);
        }
        __syncthreads();
    }

    // ---- epilogue ----
    #pragma unroll
    for (int m = 0; m < 4; ++m) {
        #pragma unroll
        for (int n = 0; n < 4; ++n) {
            #pragma unroll
            for (int j = 0; j < 4; ++j) {
                int row = tm * 128 + wr * 64 + m * 16 + kq * 4 + j;
                int col = tn * 128 + wc * 64 + n * 16 + r15;
                if (row < M) {
                    float v = acc[m][n][j];
                    if (BIAS) v += bias[col];
                    if (RELU) v = fmaxf(v, 0.f);
                    if (OMODE == 1)
                        ((ushort*)Cout)[(size_t)row * N + col] = f2bf(v);
                    else if (OMODE == 2)
                        ((float*)Cout)[(size_t)blockIdx.y * M * N + (size_t)row * N + col] = v;
                    else
                        ((float*)Cout)[(size_t)row * N + col] = v;
                }
            }
        }
    }
}

// ================= per-node attention halves (bf16 plane) =================
__global__ __launch_bounds__(256)
void attn_lr_b(const ushort* __restrict__ feat, const float* __restrict__ al,
               const float* __restrict__ ar, float* __restrict__ el,
               float* __restrict__ er, int O) {
    int n = blockIdx.x;
    int h = threadIdx.x >> 6;
    int lane = threadIdx.x & 63;
    const ushort* fr = feat + (size_t)n * (NH * O) + h * O;
    float sl = 0.f, sr = 0.f;
    for (int o = lane; o < O; o += 64) {
        float f = bf2f(fr[o]);
        sl += f * al[h * O + o];
        sr += f * ar[h * O + o];
    }
    #pragma unroll
    for (int off = 32; off; off >>= 1) {
        sl += __shfl_down(sl, off);
        sr += __shfl_down(sr, off);
    }
    if (lane == 0) {
        el[n * NH + h] = sl;
        er[n * NH + h] = sr;
    }
}

// ================= per-dst edge softmax over CSR =================
__global__ __launch_bounds__(64)
void attn_softmax(const float* __restrict__ el, const float* __restrict__ er,
                  const int* __restrict__ rowptr, const int* __restrict__ csr_src,
                  float* __restrict__ csr_e, float* __restrict__ rden) {
    int d = blockIdx.x;
    int lane = threadIdx.x;
    int base = rowptr[d], end = rowptr[d + 1];
    float erd[NH];
    #pragma unroll
    for (int h = 0; h < NH; ++h) erd[h] = er[d * NH + h];

    float mx[NH] = {-INFINITY, -INFINITY, -INFINITY, -INFINITY};
    for (int s = base + lane; s < end; s += 64) {
        int sn = csr_src[s];
        #pragma unroll
        for (int h = 0; h < NH; ++h) {
            float v = el[sn * NH + h] + erd[h];
            v = (v >= 0.f) ? v : NEG_SLOPE * v;
            csr_e[s * NH + h] = v;
            mx[h] = fmaxf(mx[h], v);
        }
    }
    #pragma unroll
    for (int h = 0; h < NH; ++h)
        #pragma unroll
        for (int off = 32; off; off >>= 1)
            mx[h] = fmaxf(mx[h], __shfl_xor(mx[h], off));

    float sm[NH] = {0.f, 0.f, 0.f, 0.f};
    for (int s = base + lane; s < end; s += 64) {
        #pragma unroll
        for (int h = 0; h < NH; ++h) {
            float ex = expf(csr_e[s * NH + h] - mx[h]);
            csr_e[s * NH + h] = ex;
            sm[h] += ex;
        }
    }
    #pragma unroll
    for (int h = 0; h < NH; ++h)
        #pragma unroll
        for (int off = 32; off; off >>= 1)
            sm[h] += __shfl_xor(sm[h], off);

    if (lane == 0) {
        #pragma unroll
        for (int h = 0; h < NH; ++h)
            rden[d * NH + h] = 1.f / fmaxf(sm[h], 1e-9f);
    }
}

// ================= gather aggregation (bf16 feat plane), 4-deep ILP ==========
// 128 threads; thread t owns cols [t*REGS, (t+1)*REGS); D = 128*REGS.
template<int REGS, int OSHIFT>
__global__ __launch_bounds__(128)
void aggregate_b(const ushort* __restrict__ feat, const float* __restrict__ csr_e,
                 const float* __restrict__ rden, const int* __restrict__ rowptr,
                 const int* __restrict__ csr_src, const float* __restrict__ bias,
                 ushort* __restrict__ Ssp, int D) {
    using VT = typename VecU<REGS>::T;
    int d = blockIdx.x;
    int t = threadIdx.x;
    int base = rowptr[d], end = rowptr[d + 1];
    const int col0 = t * REGS;
    const int h = col0 >> OSHIFT;

    float acc[REGS];
    #pragma unroll
    for (int k = 0; k < REGS; ++k) acc[k] = 0.f;

    int s = base;
    for (; s + 3 < end; s += 4) {
        int sn0 = csr_src[s], sn1 = csr_src[s + 1];
        int sn2 = csr_src[s + 2], sn3 = csr_src[s + 3];
        float a0 = csr_e[s * NH + h],       a1 = csr_e[(s + 1) * NH + h];
        float a2 = csr_e[(s + 2) * NH + h], a3 = csr_e[(s + 3) * NH + h];
        VT u0 = *(const VT*)(feat + (size_t)sn0 * D + col0);
        VT u1 = *(const VT*)(feat + (size_t)sn1 * D + col0);
        VT u2 = *(const VT*)(feat + (size_t)sn2 * D + col0);
        VT u3 = *(const VT*)(feat + (size_t)sn3 * D + col0);
        #pragma unroll
        for (int k = 0; k < REGS; ++k) acc[k] += bf2f(u0[k]) * a0;
        #pragma unroll
        for (int k = 0; k < REGS; ++k) acc[k] += bf2f(u1[k]) * a1;
        #pragma unroll
        for (int k = 0; k < REGS; ++k) acc[k] += bf2f(u2[k]) * a2;
        #pragma unroll
        for (int k = 0; k < REGS; ++k) acc[k] += bf2f(u3[k]) * a3;
    }
    if (s + 1 < end) {
        int sn0 = csr_src[s], sn1 = csr_src[s + 1];
        float a0 = csr_e[s * NH + h], a1 = csr_e[(s + 1) * NH + h];
        VT u0 = *(const VT*)(feat + (size_t)sn0 * D + col0);
        VT u1 = *(const VT*)(feat + (size_t)sn1 * D + col0);
        #pragma unroll
        for (int k = 0; k < REGS; ++k) acc[k] += bf2f(u0[k]) * a0;
        #pragma unroll
        for (int k = 0; k < REGS; ++k) acc[k] += bf2f(u1[k]) * a1;
        s += 2;
    }
    if (s < end) {
        int sn = csr_src[s];
        float a = csr_e[s * NH + h];
        VT u = *(const VT*)(feat + (size_t)sn * D + col0);
        #pragma unroll
        for (int k = 0; k < REGS; ++k) acc[k] += bf2f(u[k]) * a;
    }

    float rd = rden[d * NH + h];
    ushort hh[REGS], ll[REGS];
    #pragma unroll
    for (int k = 0; k < REGS; ++k) {
        float v = acc[k] * rd + bias[col0 + k];
        v = (v > 0.f) ? v : expm1f(v);
        bsplit(v, hh[k], ll[k]);
    }
    ushort* hrow = Ssp + (size_t)d * 2 * D;
    #pragma unroll
    for (int k = 0; k < REGS; ++k) {
        hrow[col0 + k] = hh[k];
        hrow[D + col0 + k] = ll[k];
    }
}

// ================= gate reduce: partials -> gate scalar =================
__global__ __launch_bounds__(128)
void gate_reduce(const float* __restrict__ part, const float* __restrict__ bg1,
                 const float* __restrict__ Wg2, const float* __restrict__ bg2,
                 float* __restrict__ gate) {
    int n = blockIdx.x;
    int t = threadIdx.x;
    constexpr size_t CH = (size_t)N_NODES * HIDG;
    size_t idx = (size_t)n * HIDG + t;
    float v = part[idx] + part[CH + idx] + part[2 * CH + idx] + part[3 * CH + idx] + bg1[t];
    v = fmaxf(v, 0.f) * Wg2[t];
    __shared__ float red[128];
    red[t] = v;
    __syncthreads();
    for (int s = 64; s; s >>= 1) {
        if (t < s) red[t] += red[t + s];
        __syncthreads();
    }
    if (t == 0) gate[n] = red[0] + bg2[0];
}

__global__ __launch_bounds__(64)
void gate_stats(const float* __restrict__ gate, const int* __restrict__ gptr,
                float* __restrict__ anorm) {
    int g = blockIdx.x;
    int lane = threadIdx.x;
    int s = gptr[g], e = gptr[g + 1];
    float m = -INFINITY;
    for (int n = s + lane; n < e; n += 64) m = fmaxf(m, gate[n]);
    #pragma unroll
    for (int off = 32; off; off >>= 1) m = fmaxf(m, __shfl_xor(m, off));
    float sum = 0.f;
    for (int n = s + lane; n < e; n += 64) sum += expf(gate[n] - m);
    #pragma unroll
    for (int off = 32; off; off >>= 1) sum += __shfl_xor(sum, off);
    float inv = 1.f / fmaxf(sum, 1e-9f);
    for (int n = s + lane; n < e; n += 64) anorm[n] = expf(gate[n] - m) * inv;
}

// gemb[g] = sum_n anorm[n] * h3[n]  (h3 split bf16), 4-deep ILP, ushort2 cols
__global__ __launch_bounds__(256)
void pool_gather(const ushort* __restrict__ h3sp, const float* __restrict__ anorm,
                 const int* __restrict__ gptr, float* __restrict__ gemb) {
    int g = blockIdx.y;
    int col = (blockIdx.x * 256 + threadIdx.x) * 2;
    float acc0 = 0.f, acc1 = 0.f;
    int s = gptr[g], e = gptr[g + 1];
    int n = s;
    for (; n + 3 < e; n += 4) {
        const ushort* r0 = h3sp + (size_t)(n + 0) * 2 * D3;
        const ushort* r1 = h3sp + (size_t)(n + 1) * 2 * D3;
        const ushort* r2 = h3sp + (size_t)(n + 2) * 2 * D3;
        const ushort* r3 = h3sp + (size_t)(n + 3) * 2 * D3;
        float a0 = anorm[n], a1 = anorm[n + 1], a2 = anorm[n + 2], a3 = anorm[n + 3];
        ushortx2 h0 = *(const ushortx2*)(r0 + col), l0 = *(const ushortx2*)(r0 + D3 + col);
        ushortx2 h1 = *(const ushortx2*)(r1 + col), l1 = *(const ushortx2*)(r1 + D3 + col);
        ushortx2 h2 = *(const ushortx2*)(r2 + col), l2 = *(const ushortx2*)(r2 + D3 + col);
        ushortx2 h3 = *(const ushortx2*)(r3 + col), l3 = *(const ushortx2*)(r3 + D3 + col);
        acc0 += a0 * (bf2f(h0[0]) + bf2f(l0[0])); acc1 += a0 * (bf2f(h0[1]) + bf2f(l0[1]));
        acc0 += a1 * (bf2f(h1[0]) + bf2f(l1[0])); acc1 += a1 * (bf2f(h1[1]) + bf2f(l1[1]));
        acc0 += a2 * (bf2f(h2[0]) + bf2f(l2[0])); acc1 += a2 * (bf2f(h2[1]) + bf2f(l2[1]));
        acc0 += a3 * (bf2f(h3[0]) + bf2f(l3[0])); acc1 += a3 * (bf2f(h3[1]) + bf2f(l3[1]));
    }
    for (; n < e; ++n) {
        const ushort* r0 = h3sp + (size_t)n * 2 * D3;
        float a0 = anorm[n];
        ushortx2 h0 = *(const ushortx2*)(r0 + col), l0 = *(const ushortx2*)(r0 + D3 + col);
        acc0 += a0 * (bf2f(h0[0]) + bf2f(l0[0]));
        acc1 += a0 * (bf2f(h0[1]) + bf2f(l0[1]));
    }
    gemb[(size_t)g * D3 + col] = acc0;
    gemb[(size_t)g * D3 + col + 1] = acc1;
}

// ================= heads =================
__global__ __launch_bounds__(128)
void heads_kernel(const float* __restrict__ gemb, const float* __restrict__ Wmu,
                  const float* __restrict__ bmu, const float* __restrict__ Wlv,
                  const float* __restrict__ blv, float* __restrict__ out) {
    int g = blockIdx.x;
    int j = threadIdx.x;
    __shared__ float e[D3];
    for (int k = threadIdx.x; k < D3; k += 128) e[k] = gemb[(size_t)g * D3 + k];
    __syncthreads();
    float smu = 0.f, slv = 0.f;
    for (int k = 0; k < D3; ++k) {
        float v = e[k];
        smu += v * Wmu[k * LAT + j];
        slv += v * Wlv[k * LAT + j];
    }
    out[g * LAT + j] = smu + bmu[j];
    out[N_GRAPH * LAT + g * LAT + j] = slv + blv[j];
}

// ================= host launch =================
extern "C" void kernel_launch(void* const* d_in, const int* in_sizes, int n_in,
                              void* d_out, int out_size, void* d_ws, size_t ws_size,
                              hipStream_t stream) {
    const float* node_feat = (const float*)d_in[0];
    const int*   src = (const int*)d_in[1];
    const int*   dst = (const int*)d_in[2];
    const int*   gid = (const int*)d_in[3];
    const float* W1  = (const float*)d_in[4];
    const float* al1 = (const float*)d_in[5];
    const float* ar1 = (const float*)d_in[6];
    const float* b1  = (const float*)d_in[7];
    const float* W2  = (const float*)d_in[8];
    const float* al2 = (const float*)d_in[9];
    const float* ar2 = (const float*)d_in[10];
    const float* b2  = (const float*)d_in[11];
    const float* W3  = (const float*)d_in[12];
    const float* al3 = (const float*)d_in[13];
    const float* ar3 = (const float*)d_in[14];
    const float* b3  = (const float*)d_in[15];
    const float* Wg1 = (const float*)d_in[16];
    const float* bg1 = (const float*)d_in[17];
    const float* Wg2 = (const float*)d_in[18];
    const float* bg2 = (const float*)d_in[19];
    const float* Wmu = (const float*)d_in[20];
    const float* bmu = (const float*)d_in[21];
    const float* Wlv = (const float*)d_in[22];
    const float* blv = (const float*)d_in[23];
    float* out = (float*)d_out;

    // ---- workspace carve ----
    char* wsb = (char*)d_ws;
    float* bufA   = (float*)wsb;                                   // N*D3 f32 region
    wsb += (size_t)N_NODES * D3 * 4;
    ushort* Xsp   = (ushort*)wsb;                                  // N*2048 bf16 (split acts)
    wsb += (size_t)N_NODES * 2048 * 2;
    ushort* Bt1   = (ushort*)wsb; wsb += (size_t)D1 * 2 * F_IN * 2;
    ushort* Bt2   = (ushort*)wsb; wsb += (size_t)D2 * 2 * D1 * 2;
    ushort* Bt3   = (ushort*)wsb; wsb += (size_t)D3 * 2 * D2 * 2;
    ushort* Btg   = (ushort*)wsb; wsb += (size_t)HIDG * 2 * D3 * 2;
    float* el     = (float*)wsb;  wsb += (size_t)N_NODES * NH * 4;
    float* er     = (float*)wsb;  wsb += (size_t)N_NODES * NH * 4;
    float* rden   = (float*)wsb;  wsb += (size_t)N_NODES * NH * 4;
    float* csr_e  = (float*)wsb;  wsb += (size_t)N_EDGES * NH * 4;
    float* gate   = (float*)wsb;  wsb += (size_t)N_NODES * 4;
    float* anorm  = (float*)wsb;  wsb += (size_t)N_NODES * 4;
    int* deg      = (int*)wsb;    wsb += (size_t)N_NODES * 4;
    int* rowptr   = (int*)wsb;    wsb += (size_t)(N_NODES + 1) * 4;
    int* pos      = (int*)wsb;    wsb += (size_t)N_NODES * 4;
    int* csr_src  = (int*)wsb;    wsb += (size_t)N_EDGES * 4;
    int* bsum     = (int*)wsb;    wsb += 64 * 4;
    int* boff     = (int*)wsb;    wsb += 64 * 4;
    int* gptr     = (int*)wsb;    wsb += (size_t)(N_GRAPH + 1) * 4;
    ushort* featb = (ushort*)bufA;                                 // bf16 feat plane alias
    float* partial = bufA;                                         // pool K-split partials (4*N*128)
    float* gemb   = bufA + (size_t)4 * N_NODES * HIDG;             // G*D3

    // ---- CSR build ----
    constexpr int NBLK = (N_NODES + SCAN_B - 1) / SCAN_B;
    zero_int<<<dim3((N_NODES + 255) / 256), dim3(256), 0, stream>>>(deg, N_NODES);
    count_deg<<<dim3((N_EDGES + 255) / 256), dim3(256), 0, stream>>>(dst, deg);
    scan1<<<dim3(NBLK), dim3(SCAN_B), 0, stream>>>(deg, rowptr, bsum);
    scan2<<<dim3(1), dim3(64), 0, stream>>>(bsum, boff, NBLK);
    scan3<<<dim3(NBLK), dim3(SCAN_B), 0, stream>>>(rowptr, boff, pos);
    fill_csr<<<dim3((N_EDGES + 255) / 256), dim3(256), 0, stream>>>(src, dst, pos, csr_src);
    gptr_kernel<<<dim3(1), dim3(256), 0, stream>>>(gid, gptr);

    // ---- weight splits (transposed) ----
    split_wt<<<dim3(D1 / 32, F_IN / 32), dim3(32, 8), 0, stream>>>(W1, Bt1, F_IN, D1);
    split_wt<<<dim3(D2 / 32, D1 / 32),   dim3(32, 8), 0, stream>>>(W2, Bt2, D1, D2);
    split_wt<<<dim3(D3 / 32, D2 / 32),   dim3(32, 8), 0, stream>>>(W3, Bt3, D2, D3);
    split_wt<<<dim3(HIDG / 32, D3 / 32), dim3(32, 8), 0, stream>>>(Wg1, Btg, D3, HIDG);

    // ---- layer-1 input split ----
    split_x<<<dim3((N_NODES * F_IN / 4 + 255) / 256), dim3(256), 0, stream>>>(node_feat, Xsp, N_NODES, F_IN);

    // ---- layer 1 ----
    gemm_mfma<false, false, 1><<<dim3(157 * 2), dim3(256), 0, stream>>>(Xsp, Bt1, nullptr, featb, N_NODES, D1, F_IN, 2, F_IN);
    attn_lr_b<<<dim3(N_NODES), dim3(256), 0, stream>>>(featb, al1, ar1, el, er, O1);
    attn_softmax<<<dim3(N_NODES), dim3(64), 0, stream>>>(el, er, rowptr, csr_src, csr_e, rden);
    aggregate_b<2, 6><<<dim3(N_NODES), dim3(128), 0, stream>>>(featb, csr_e, rden, rowptr, csr_src, b1, Xsp, D1);

    // ---- layer 2 ----
    gemm_mfma<false, false, 1><<<dim3(157 * 4), dim3(256), 0, stream>>>(Xsp, Bt2, nullptr, featb, N_NODES, D2, D1, 4, D1);
    attn_lr_b<<<dim3(N_NODES), dim3(256), 0, stream>>>(featb, al2, ar2, el, er, O2);
    attn_softmax<<<dim3(N_NODES), dim3(64), 0, stream>>>(el, er, rowptr, csr_src, csr_e, rden);
    aggregate_b<4, 7><<<dim3(N_NODES), dim3(128), 0, stream>>>(featb, csr_e, rden, rowptr, csr_src, b2, Xsp, D2);

    // ---- layer 3 ----
    gemm_mfma<false, false, 1><<<dim3(157 * 8), dim3(256), 0, stream>>>(Xsp, Bt3, nullptr, featb, N_NODES, D3, D2, 8, D2);
    attn_lr_b<<<dim3(N_NODES), dim3(256), 0, stream>>>(featb, al3, ar3, el, er, O3);
    attn_softmax<<<dim3(N_NODES), dim3(64), 0, stream>>>(el, er, rowptr, csr_src, csr_e, rden);
    aggregate_b<8, 8><<<dim3(N_NODES), dim3(128), 0, stream>>>(featb, csr_e, rden, rowptr, csr_src, b3, Xsp, D3);

    // ---- pooling: K-split x4 gate GEMM -> fused reduce ----
    gemm_mfma<false, false, 2><<<dim3(157, 4), dim3(256), 0, stream>>>(Xsp, Btg, nullptr, partial, N_NODES, HIDG, D3, 1, D3 / 4);
    gate_reduce<<<dim3(N_NODES), dim3(128), 0, stream>>>(partial, bg1, Wg2, bg2, gate);
    gate_stats<<<dim3(N_GRAPH), dim3(64), 0, stream>>>(gate, gptr, anorm);
    pool_gather<<<dim3(D3 / 512, N_GRAPH), dim3(256), 0, stream>>>(Xsp, anorm, gptr, gemb);
    heads_kernel<<<dim3(N_GRAPH), dim3(128), 0, stream>>>(gemb, Wmu, bmu, Wlv, blv, out);
}